// Round 1
// baseline (334.541 us; speedup 1.0000x reference)
//
#include <hip/hip_runtime.h>

#define N_NODES 40000
#define N_EDGES 640000
#define D 128

// ---------------- CSR build ----------------

__global__ void count_deg(const int* __restrict__ dst, int* __restrict__ deg) {
    int e = blockIdx.x * 256 + threadIdx.x;
    if (e < N_EDGES) atomicAdd(&deg[dst[e]], 1);
}

__global__ void scan_kernel(const int* __restrict__ deg,
                            int* __restrict__ row_start,
                            int* __restrict__ cursor) {
    __shared__ int sums[1024];
    int t = threadIdx.x;
    const int per = (N_NODES + 1023) / 1024;  // 40
    int lo = t * per;
    int hi = min(lo + per, N_NODES);
    int s = 0;
    for (int i = lo; i < hi; ++i) s += deg[i];
    sums[t] = s;
    __syncthreads();
    // Hillis-Steele inclusive scan (read old, barrier, write, barrier)
    for (int off = 1; off < 1024; off <<= 1) {
        int v = 0;
        if (t >= off) v = sums[t - off];
        __syncthreads();
        if (t >= off) sums[t] += v;
        __syncthreads();
    }
    int base = (t == 0) ? 0 : sums[t - 1];
    for (int i = lo; i < hi; ++i) {
        int d = deg[i];
        row_start[i] = base;
        cursor[i] = base;
        base += d;
    }
    if (t == 1023) row_start[N_NODES] = sums[1023];
}

__global__ void fill_edges(const int* __restrict__ src, const int* __restrict__ dst,
                           int* __restrict__ cursor, int* __restrict__ edge_src) {
    int e = blockIdx.x * 256 + threadIdx.x;
    if (e < N_EDGES) {
        int p = atomicAdd(&cursor[dst[e]], 1);
        edge_src[p] = src[e];
    }
}

// ---------------- mean aggregation ----------------
// one wave per dst node; lane handles cols 2*lane, 2*lane+1 (float2)

__global__ __launch_bounds__(256) void agg_mean(
    const float* __restrict__ h, const int* __restrict__ row_start,
    const int* __restrict__ edge_src, float* __restrict__ mean_out) {
    int wave = threadIdx.x >> 6;
    int lane = threadIdx.x & 63;
    int n = blockIdx.x * 4 + wave;
    if (n >= N_NODES) return;
    int e0 = row_start[n], e1 = row_start[n + 1];
    const float2* h2 = (const float2*)h;
    float2 acc0 = {0.f, 0.f}, acc1 = {0.f, 0.f};
    int e = e0;
    for (; e + 1 < e1; e += 2) {
        int s0 = edge_src[e];
        int s1 = edge_src[e + 1];
        float2 v0 = h2[(size_t)s0 * 64 + lane];
        float2 v1 = h2[(size_t)s1 * 64 + lane];
        acc0.x += v0.x; acc0.y += v0.y;
        acc1.x += v1.x; acc1.y += v1.y;
    }
    if (e < e1) {
        int s0 = edge_src[e];
        float2 v0 = h2[(size_t)s0 * 64 + lane];
        acc0.x += v0.x; acc0.y += v0.y;
    }
    float cnt = (float)(e1 - e0);
    float inv = cnt > 0.f ? 1.0f / cnt : 0.f;
    float2 r;
    r.x = (acc0.x + acc1.x) * inv;
    r.y = (acc0.y + acc1.y) * inv;
    ((float2*)mean_out)[(size_t)n * 64 + lane] = r;
}

// ---------------- fused dual GEMM ----------------
// C[M x 128] = maybe_relu( A1 @ W1 + A2 @ W2 + b )
// A1, A2: [M x 128] f32; W1, W2: [128 x 128] f32
// BM=64 rows/block, all 128 cols, BK=32, 256 threads, 32 outputs/thread

#define BM 64
#define BK 32

__global__ __launch_bounds__(256) void gemm_fused(
    const float* __restrict__ A1, const float* __restrict__ A2,
    const float* __restrict__ W1, const float* __restrict__ W2,
    const float* __restrict__ bias, float* __restrict__ C, int do_relu) {
    __shared__ float As[BK][BM + 4];   // transposed A tile, +4 pad keeps float4 align, spreads banks
    __shared__ float Bs[BK][128];

    int tid = threadIdx.x;
    int row0 = blockIdx.x * BM;
    int cx = tid & 31;   // col group: cols cx*4 .. +3
    int ry = tid >> 5;   // row group: rows ry*8 .. +7

    float acc[8][4] = {};

    for (int kk = 0; kk < 256; kk += BK) {
        const float* A = (kk < 128) ? A1 : A2;
        const float* W = (kk < 128) ? W1 : W2;
        int kbase = kk & 127;

        // stage A chunk (64 rows x 32 k), store transposed
        {
            int r  = tid >> 3;          // 0..31
            int kq = (tid & 7) << 2;    // 0,4,...,28
            #pragma unroll
            for (int hh = 0; hh < 2; ++hh) {
                int rr = r + 32 * hh;
                float4 v = *(const float4*)&A[(size_t)(row0 + rr) * D + kbase + kq];
                As[kq + 0][rr] = v.x;
                As[kq + 1][rr] = v.y;
                As[kq + 2][rr] = v.z;
                As[kq + 3][rr] = v.w;
            }
        }
        // stage B chunk (32 k x 128 cols)
        {
            int kr = tid >> 5;          // 0..7
            int cq = (tid & 31) << 2;   // 0..124
            #pragma unroll
            for (int hh = 0; hh < 4; ++hh) {
                int k = kr + 8 * hh;
                float4 v = *(const float4*)&W[(size_t)(kbase + k) * D + cq];
                *(float4*)&Bs[k][cq] = v;
            }
        }
        __syncthreads();

        #pragma unroll
        for (int k = 0; k < BK; ++k) {
            float4 a0 = *(const float4*)&As[k][ry * 8];
            float4 a1 = *(const float4*)&As[k][ry * 8 + 4];
            float4 bv = *(const float4*)&Bs[k][cx * 4];
            float av[8] = {a0.x, a0.y, a0.z, a0.w, a1.x, a1.y, a1.z, a1.w};
            float bvv[4] = {bv.x, bv.y, bv.z, bv.w};
            #pragma unroll
            for (int i = 0; i < 8; ++i)
                #pragma unroll
                for (int j = 0; j < 4; ++j)
                    acc[i][j] += av[i] * bvv[j];
        }
        __syncthreads();
    }

    float4 bv = *(const float4*)&bias[cx * 4];
    float bvv[4] = {bv.x, bv.y, bv.z, bv.w};
    #pragma unroll
    for (int i = 0; i < 8; ++i) {
        int row = row0 + ry * 8 + i;
        float4 o;
        o.x = acc[i][0] + bvv[0];
        o.y = acc[i][1] + bvv[1];
        o.z = acc[i][2] + bvv[2];
        o.w = acc[i][3] + bvv[3];
        if (do_relu) {
            o.x = fmaxf(o.x, 0.f); o.y = fmaxf(o.y, 0.f);
            o.z = fmaxf(o.z, 0.f); o.w = fmaxf(o.w, 0.f);
        }
        *(float4*)&C[(size_t)row * D + cx * 4] = o;
    }
}

// ---------------- launch ----------------

extern "C" void kernel_launch(void* const* d_in, const int* in_sizes, int n_in,
                              void* d_out, int out_size, void* d_ws, size_t ws_size,
                              hipStream_t stream) {
    const float* x       = (const float*)d_in[0];
    const int*   src     = (const int*)d_in[1];
    const int*   dst     = (const int*)d_in[2];
    const float* W_self1 = (const float*)d_in[3];
    const float* W_neigh1= (const float*)d_in[4];
    const float* b1      = (const float*)d_in[5];
    const float* W_self2 = (const float*)d_in[6];
    const float* W_neigh2= (const float*)d_in[7];
    const float* b2      = (const float*)d_in[8];
    float* out = (float*)d_out;

    // workspace layout
    char* ws = (char*)d_ws;
    size_t off_deg  = 0;                       // 40000 int
    size_t off_rs   = off_deg + 160000;        // 40001 int
    size_t off_cur  = off_rs + 160016;         // 40000 int
    size_t off_es   = off_cur + 160000;        // 640000 int
    size_t off_mean = off_es + 2560000;        // 40000*128 f32
    size_t off_h1   = off_mean + 20480000;     // 40000*128 f32
    size_t total    = off_h1 + 20480000;
    if (ws_size < total) return;  // loud failure rather than corruption

    int* deg      = (int*)(ws + off_deg);
    int* row_start= (int*)(ws + off_rs);
    int* cursor   = (int*)(ws + off_cur);
    int* edge_src = (int*)(ws + off_es);
    float* meanb  = (float*)(ws + off_mean);
    float* h1     = (float*)(ws + off_h1);

    hipMemsetAsync(deg, 0, 160000, stream);

    count_deg<<<(N_EDGES + 255) / 256, 256, 0, stream>>>(dst, deg);
    scan_kernel<<<1, 1024, 0, stream>>>(deg, row_start, cursor);
    fill_edges<<<(N_EDGES + 255) / 256, 256, 0, stream>>>(src, dst, cursor, edge_src);

    // layer 1
    agg_mean<<<N_NODES / 4, 256, 0, stream>>>(x, row_start, edge_src, meanb);
    gemm_fused<<<N_NODES / BM, 256, 0, stream>>>(x, meanb, W_self1, W_neigh1, b1, h1, 1);

    // layer 2
    agg_mean<<<N_NODES / 4, 256, 0, stream>>>(h1, row_start, edge_src, meanb);
    gemm_fused<<<N_NODES / BM, 256, 0, stream>>>(h1, meanb, W_self2, W_neigh2, b2, out, 0);
}

// Round 2
// 256.823 us; speedup vs baseline: 1.3026x; 1.3026x over previous
//
#include <hip/hip_runtime.h>

#define N_NODES 40000
#define N_EDGES 640000
#define D 128

// ---------------- CSR build ----------------

__global__ void count_deg(const int* __restrict__ dst, int* __restrict__ deg) {
    int e = blockIdx.x * 256 + threadIdx.x;
    if (e < N_EDGES) atomicAdd(&deg[dst[e]], 1);
}

// 3-phase parallel exclusive scan over deg[N_NODES]
#define SCAN_CHUNK 256
#define SCAN_NBLK ((N_NODES + SCAN_CHUNK - 1) / SCAN_CHUNK)  // 157

// phase 1: per-block scan. row_start[i] <- local exclusive scan value,
//          block_sums[b] <- block total
__global__ __launch_bounds__(256) void scan_phase1(
    const int* __restrict__ deg, int* __restrict__ row_start,
    int* __restrict__ block_sums) {
    __shared__ int s[SCAN_CHUNK];
    int t = threadIdx.x;
    int i = blockIdx.x * SCAN_CHUNK + t;
    int v = (i < N_NODES) ? deg[i] : 0;
    s[t] = v;
    __syncthreads();
    for (int off = 1; off < SCAN_CHUNK; off <<= 1) {
        int u = 0;
        if (t >= off) u = s[t - off];
        __syncthreads();
        if (t >= off) s[t] += u;
        __syncthreads();
    }
    if (i < N_NODES) row_start[i] = s[t] - v;  // exclusive
    if (t == SCAN_CHUNK - 1) block_sums[blockIdx.x] = s[t];
}

// phase 2: scan the 157 block sums (one block), convert to exclusive offsets,
//          write row_start[N_NODES] = grand total
__global__ __launch_bounds__(256) void scan_phase2(
    int* __restrict__ block_sums, int* __restrict__ row_start) {
    __shared__ int s[256];
    int t = threadIdx.x;
    int v = (t < SCAN_NBLK) ? block_sums[t] : 0;
    s[t] = v;
    __syncthreads();
    for (int off = 1; off < 256; off <<= 1) {
        int u = 0;
        if (t >= off) u = s[t - off];
        __syncthreads();
        if (t >= off) s[t] += u;
        __syncthreads();
    }
    if (t < SCAN_NBLK) block_sums[t] = s[t] - v;  // exclusive offset
    if (t == SCAN_NBLK - 1) row_start[N_NODES] = s[t];
}

// phase 3: add block offsets, mirror into cursor
__global__ __launch_bounds__(256) void scan_phase3(
    const int* __restrict__ block_sums, int* __restrict__ row_start,
    int* __restrict__ cursor) {
    int i = blockIdx.x * SCAN_CHUNK + threadIdx.x;
    if (i < N_NODES) {
        int v = row_start[i] + block_sums[blockIdx.x];
        row_start[i] = v;
        cursor[i] = v;
    }
}

__global__ void fill_edges(const int* __restrict__ src, const int* __restrict__ dst,
                           int* __restrict__ cursor, int* __restrict__ edge_src) {
    int e = blockIdx.x * 256 + threadIdx.x;
    if (e < N_EDGES) {
        int p = atomicAdd(&cursor[dst[e]], 1);
        edge_src[p] = src[e];
    }
}

// ---------------- mean aggregation ----------------
// one wave per dst node; lane handles cols 2*lane, 2*lane+1 (float2)

__global__ __launch_bounds__(256) void agg_mean(
    const float* __restrict__ h, const int* __restrict__ row_start,
    const int* __restrict__ edge_src, float* __restrict__ mean_out) {
    int wave = threadIdx.x >> 6;
    int lane = threadIdx.x & 63;
    int n = blockIdx.x * 4 + wave;
    if (n >= N_NODES) return;
    int e0 = row_start[n], e1 = row_start[n + 1];
    const float2* h2 = (const float2*)h;
    float2 acc0 = {0.f, 0.f}, acc1 = {0.f, 0.f};
    int e = e0;
    for (; e + 1 < e1; e += 2) {
        int s0 = edge_src[e];
        int s1 = edge_src[e + 1];
        float2 v0 = h2[(size_t)s0 * 64 + lane];
        float2 v1 = h2[(size_t)s1 * 64 + lane];
        acc0.x += v0.x; acc0.y += v0.y;
        acc1.x += v1.x; acc1.y += v1.y;
    }
    if (e < e1) {
        int s0 = edge_src[e];
        float2 v0 = h2[(size_t)s0 * 64 + lane];
        acc0.x += v0.x; acc0.y += v0.y;
    }
    float cnt = (float)(e1 - e0);
    float inv = cnt > 0.f ? 1.0f / cnt : 0.f;
    float2 r;
    r.x = (acc0.x + acc1.x) * inv;
    r.y = (acc0.y + acc1.y) * inv;
    ((float2*)mean_out)[(size_t)n * 64 + lane] = r;
}

// ---------------- fused dual GEMM ----------------
// C[M x 128] = maybe_relu( A1 @ W1 + A2 @ W2 + b )

#define BM 64
#define BK 32

__global__ __launch_bounds__(256) void gemm_fused(
    const float* __restrict__ A1, const float* __restrict__ A2,
    const float* __restrict__ W1, const float* __restrict__ W2,
    const float* __restrict__ bias, float* __restrict__ C, int do_relu) {
    __shared__ float As[BK][BM + 4];
    __shared__ float Bs[BK][128];

    int tid = threadIdx.x;
    int row0 = blockIdx.x * BM;
    int cx = tid & 31;
    int ry = tid >> 5;

    float acc[8][4] = {};

    for (int kk = 0; kk < 256; kk += BK) {
        const float* A = (kk < 128) ? A1 : A2;
        const float* W = (kk < 128) ? W1 : W2;
        int kbase = kk & 127;

        {
            int r  = tid >> 3;
            int kq = (tid & 7) << 2;
            #pragma unroll
            for (int hh = 0; hh < 2; ++hh) {
                int rr = r + 32 * hh;
                float4 v = *(const float4*)&A[(size_t)(row0 + rr) * D + kbase + kq];
                As[kq + 0][rr] = v.x;
                As[kq + 1][rr] = v.y;
                As[kq + 2][rr] = v.z;
                As[kq + 3][rr] = v.w;
            }
        }
        {
            int kr = tid >> 5;
            int cq = (tid & 31) << 2;
            #pragma unroll
            for (int hh = 0; hh < 4; ++hh) {
                int k = kr + 8 * hh;
                float4 v = *(const float4*)&W[(size_t)(kbase + k) * D + cq];
                *(float4*)&Bs[k][cq] = v;
            }
        }
        __syncthreads();

        #pragma unroll
        for (int k = 0; k < BK; ++k) {
            float4 a0 = *(const float4*)&As[k][ry * 8];
            float4 a1 = *(const float4*)&As[k][ry * 8 + 4];
            float4 bv = *(const float4*)&Bs[k][cx * 4];
            float av[8] = {a0.x, a0.y, a0.z, a0.w, a1.x, a1.y, a1.z, a1.w};
            float bvv[4] = {bv.x, bv.y, bv.z, bv.w};
            #pragma unroll
            for (int i = 0; i < 8; ++i)
                #pragma unroll
                for (int j = 0; j < 4; ++j)
                    acc[i][j] += av[i] * bvv[j];
        }
        __syncthreads();
    }

    float4 bv = *(const float4*)&bias[cx * 4];
    float bvv[4] = {bv.x, bv.y, bv.z, bv.w};
    #pragma unroll
    for (int i = 0; i < 8; ++i) {
        int row = row0 + ry * 8 + i;
        float4 o;
        o.x = acc[i][0] + bvv[0];
        o.y = acc[i][1] + bvv[1];
        o.z = acc[i][2] + bvv[2];
        o.w = acc[i][3] + bvv[3];
        if (do_relu) {
            o.x = fmaxf(o.x, 0.f); o.y = fmaxf(o.y, 0.f);
            o.z = fmaxf(o.z, 0.f); o.w = fmaxf(o.w, 0.f);
        }
        *(float4*)&C[(size_t)row * D + cx * 4] = o;
    }
}

// ---------------- launch ----------------

extern "C" void kernel_launch(void* const* d_in, const int* in_sizes, int n_in,
                              void* d_out, int out_size, void* d_ws, size_t ws_size,
                              hipStream_t stream) {
    const float* x       = (const float*)d_in[0];
    const int*   src     = (const int*)d_in[1];
    const int*   dst     = (const int*)d_in[2];
    const float* W_self1 = (const float*)d_in[3];
    const float* W_neigh1= (const float*)d_in[4];
    const float* b1      = (const float*)d_in[5];
    const float* W_self2 = (const float*)d_in[6];
    const float* W_neigh2= (const float*)d_in[7];
    const float* b2      = (const float*)d_in[8];
    float* out = (float*)d_out;

    // workspace layout
    char* ws = (char*)d_ws;
    size_t off_deg  = 0;                       // 40000 int
    size_t off_rs   = off_deg + 160000;        // 40001 int
    size_t off_cur  = off_rs + 160016;         // 40000 int
    size_t off_es   = off_cur + 160000;        // 640000 int
    size_t off_mean = off_es + 2560000;        // 40000*128 f32
    size_t off_h1   = off_mean + 20480000;     // 40000*128 f32
    size_t off_bs   = off_h1 + 20480000;       // 157 int (block sums)
    size_t total    = off_bs + 640;
    if (ws_size < total) return;

    int* deg      = (int*)(ws + off_deg);
    int* row_start= (int*)(ws + off_rs);
    int* cursor   = (int*)(ws + off_cur);
    int* edge_src = (int*)(ws + off_es);
    float* meanb  = (float*)(ws + off_mean);
    float* h1     = (float*)(ws + off_h1);
    int* block_sums = (int*)(ws + off_bs);

    hipMemsetAsync(deg, 0, 160000, stream);

    count_deg<<<(N_EDGES + 255) / 256, 256, 0, stream>>>(dst, deg);
    scan_phase1<<<SCAN_NBLK, 256, 0, stream>>>(deg, row_start, block_sums);
    scan_phase2<<<1, 256, 0, stream>>>(block_sums, row_start);
    scan_phase3<<<SCAN_NBLK, 256, 0, stream>>>(block_sums, row_start, cursor);
    fill_edges<<<(N_EDGES + 255) / 256, 256, 0, stream>>>(src, dst, cursor, edge_src);

    // layer 1
    agg_mean<<<N_NODES / 4, 256, 0, stream>>>(x, row_start, edge_src, meanb);
    gemm_fused<<<N_NODES / BM, 256, 0, stream>>>(x, meanb, W_self1, W_neigh1, b1, h1, 1);

    // layer 2
    agg_mean<<<N_NODES / 4, 256, 0, stream>>>(h1, row_start, edge_src, meanb);
    gemm_fused<<<N_NODES / BM, 256, 0, stream>>>(h1, meanb, W_self2, W_neigh2, b2, out, 0);
}

// Round 3
// 192.359 us; speedup vs baseline: 1.7391x; 1.3351x over previous
//
#include <hip/hip_runtime.h>

#define N_NODES 40000
#define N_EDGES 640000
#define D 128

typedef __attribute__((ext_vector_type(8))) short short8;   // 8 bf16 = 4 VGPR
typedef __attribute__((ext_vector_type(4))) float f32x4;

__device__ __forceinline__ unsigned short f2bf(float f) {
    unsigned u = __float_as_uint(f);
    unsigned r = u + 0x7FFF + ((u >> 16) & 1);   // round-to-nearest-even
    return (unsigned short)(r >> 16);
}

// ---------------- CSR build ----------------

__global__ void count_deg(const int* __restrict__ dst, int* __restrict__ deg) {
    int e = blockIdx.x * 256 + threadIdx.x;
    if (e < N_EDGES) atomicAdd(&deg[dst[e]], 1);
}

#define SCAN_CHUNK 256
#define SCAN_NBLK ((N_NODES + SCAN_CHUNK - 1) / SCAN_CHUNK)  // 157

__global__ __launch_bounds__(256) void scan_phase1(
    const int* __restrict__ deg, int* __restrict__ row_start,
    int* __restrict__ block_sums) {
    __shared__ int s[SCAN_CHUNK];
    int t = threadIdx.x;
    int i = blockIdx.x * SCAN_CHUNK + t;
    int v = (i < N_NODES) ? deg[i] : 0;
    s[t] = v;
    __syncthreads();
    for (int off = 1; off < SCAN_CHUNK; off <<= 1) {
        int u = 0;
        if (t >= off) u = s[t - off];
        __syncthreads();
        if (t >= off) s[t] += u;
        __syncthreads();
    }
    if (i < N_NODES) row_start[i] = s[t] - v;
    if (t == SCAN_CHUNK - 1) block_sums[blockIdx.x] = s[t];
}

__global__ __launch_bounds__(256) void scan_phase2(
    int* __restrict__ block_sums, int* __restrict__ row_start) {
    __shared__ int s[256];
    int t = threadIdx.x;
    int v = (t < SCAN_NBLK) ? block_sums[t] : 0;
    s[t] = v;
    __syncthreads();
    for (int off = 1; off < 256; off <<= 1) {
        int u = 0;
        if (t >= off) u = s[t - off];
        __syncthreads();
        if (t >= off) s[t] += u;
        __syncthreads();
    }
    if (t < SCAN_NBLK) block_sums[t] = s[t] - v;
    if (t == SCAN_NBLK - 1) row_start[N_NODES] = s[t];
}

__global__ __launch_bounds__(256) void scan_phase3(
    const int* __restrict__ block_sums, int* __restrict__ row_start,
    int* __restrict__ cursor) {
    int i = blockIdx.x * SCAN_CHUNK + threadIdx.x;
    if (i < N_NODES) {
        int v = row_start[i] + block_sums[blockIdx.x];
        row_start[i] = v;
        cursor[i] = v;
    }
}

__global__ void fill_edges(const int* __restrict__ src, const int* __restrict__ dst,
                           int* __restrict__ cursor, int* __restrict__ edge_src) {
    int e = blockIdx.x * 256 + threadIdx.x;
    if (e < N_EDGES) {
        int p = atomicAdd(&cursor[dst[e]], 1);
        edge_src[p] = src[e];
    }
}

// ---------------- fp32 -> bf16 conversion (8 elems/thread) ----------------

__global__ __launch_bounds__(256) void f32_to_bf16(const float* __restrict__ in,
                                                   unsigned short* __restrict__ out) {
    int i = blockIdx.x * 256 + threadIdx.x;   // i < 640000 exact
    float4 a = ((const float4*)in)[i * 2];
    float4 b = ((const float4*)in)[i * 2 + 1];
    uint4 o;
    o.x = f2bf(a.x) | ((unsigned)f2bf(a.y) << 16);
    o.y = f2bf(a.z) | ((unsigned)f2bf(a.w) << 16);
    o.z = f2bf(b.x) | ((unsigned)f2bf(b.y) << 16);
    o.w = f2bf(b.z) | ((unsigned)f2bf(b.w) << 16);
    ((uint4*)out)[i] = o;
}

// ---------------- weight pre-pack into MFMA B-fragment order ----------------
// element (((q*8+c)*64+l)*8 + j) = W[(q&3)*32 + (l>>4)*8 + j][c*16 + (l&15)]
// where q<4 -> W_self, q>=4 -> W_neigh.  One uint (j pair) per thread.

__global__ __launch_bounds__(256) void pack_W(
    const float* __restrict__ Ws1, const float* __restrict__ Wn1,
    const float* __restrict__ Ws2, const float* __restrict__ Wn2,
    unsigned* __restrict__ Wp) {          // [2][16384] uints
    int idx = blockIdx.x * 256 + threadIdx.x;   // < 32768
    int L   = idx >> 14;
    int rem = idx & 16383;
    int j2 = rem & 3;
    int l  = (rem >> 2) & 63;
    int c  = (rem >> 8) & 7;
    int q  = rem >> 11;
    const float* W = (L == 0) ? (q < 4 ? Ws1 : Wn1) : (q < 4 ? Ws2 : Wn2);
    int k0  = (q & 3) * 32 + (l >> 4) * 8 + 2 * j2;
    int col = c * 16 + (l & 15);
    float v0 = W[(size_t)k0 * D + col];
    float v1 = W[(size_t)(k0 + 1) * D + col];
    Wp[idx] = f2bf(v0) | ((unsigned)f2bf(v1) << 16);
}

// ---------------- mean aggregation (bf16 gather, fp32 accum, bf16 out) ------
// one wave per node; halves of the wave take alternating edges; lane covers
// 4 features (8 B uint2) of the 256 B bf16 row.

__global__ __launch_bounds__(256) void agg_mean_bf16(
    const unsigned short* __restrict__ hb, const int* __restrict__ row_start,
    const int* __restrict__ edge_src, unsigned short* __restrict__ mean_out) {
    int wave = threadIdx.x >> 6;
    int lane = threadIdx.x & 63;
    int n = blockIdx.x * 4 + wave;
    if (n >= N_NODES) return;
    int e0 = row_start[n], e1 = row_start[n + 1];
    int half = lane >> 5, sl = lane & 31;
    const uint2* h2 = (const uint2*)hb;       // 32 uint2 per row
    float a0 = 0.f, a1 = 0.f, a2 = 0.f, a3 = 0.f;
    int e = e0;
    for (; e + 3 < e1; e += 4) {              // 4 edges/iter (2 per half)
        int s0 = edge_src[e + half];
        int s1 = edge_src[e + 2 + half];
        uint2 v0 = h2[(size_t)s0 * 32 + sl];
        uint2 v1 = h2[(size_t)s1 * 32 + sl];
        a0 += __uint_as_float(v0.x << 16) + __uint_as_float(v1.x << 16);
        a1 += __uint_as_float(v0.x & 0xFFFF0000u) + __uint_as_float(v1.x & 0xFFFF0000u);
        a2 += __uint_as_float(v0.y << 16) + __uint_as_float(v1.y << 16);
        a3 += __uint_as_float(v0.y & 0xFFFF0000u) + __uint_as_float(v1.y & 0xFFFF0000u);
    }
    if (e + 1 < e1) {                         // 2 edges (1 per half)
        int s0 = edge_src[e + half];
        uint2 v0 = h2[(size_t)s0 * 32 + sl];
        a0 += __uint_as_float(v0.x << 16);
        a1 += __uint_as_float(v0.x & 0xFFFF0000u);
        a2 += __uint_as_float(v0.y << 16);
        a3 += __uint_as_float(v0.y & 0xFFFF0000u);
        e += 2;
    }
    if (e < e1 && half == 0) {                // last odd edge: half 0 only
        int s0 = edge_src[e];
        uint2 v0 = h2[(size_t)s0 * 32 + sl];
        a0 += __uint_as_float(v0.x << 16);
        a1 += __uint_as_float(v0.x & 0xFFFF0000u);
        a2 += __uint_as_float(v0.y << 16);
        a3 += __uint_as_float(v0.y & 0xFFFF0000u);
    }
    a0 += __shfl_xor(a0, 32, 64);
    a1 += __shfl_xor(a1, 32, 64);
    a2 += __shfl_xor(a2, 32, 64);
    a3 += __shfl_xor(a3, 32, 64);
    float cnt = (float)(e1 - e0);
    float inv = cnt > 0.f ? 1.0f / cnt : 0.f;
    if (half == 0) {
        uint2 o;
        o.x = f2bf(a0 * inv) | ((unsigned)f2bf(a1 * inv) << 16);
        o.y = f2bf(a2 * inv) | ((unsigned)f2bf(a3 * inv) << 16);
        ((uint2*)mean_out)[(size_t)n * 32 + sl] = o;
    }
}

// ---------------- bf16 MFMA dual GEMM ----------------
// C[M x 128] = maybe_relu( A1 @ W_self + A2 @ W_neigh + b )
// 64 rows/block, 4 waves, wave handles 16 rows x 128 cols.
// K = 256 as 8 chunks of 32 (q<4 from A1/W_self, q>=4 from A2/W_neigh).

__global__ __launch_bounds__(256) void gemm_mfma(
    const unsigned short* __restrict__ A1, const unsigned short* __restrict__ A2,
    const unsigned* __restrict__ Wp,      // 16384 uints, fragment order
    const float* __restrict__ bias,
    unsigned short* __restrict__ outb,    // bf16 out (layer 1) or nullptr
    float* __restrict__ outf,             // f32 out (layer 2) or nullptr
    int do_relu) {
    __shared__ float s[4][16][132];       // +4 pad
    int tid = threadIdx.x;
    int w = tid >> 6, l = tid & 63;
    int rlo = l & 15, khi = l >> 4;
    int row0 = blockIdx.x * 64 + w * 16;

    const unsigned short* ar1 = A1 + (size_t)(row0 + rlo) * D + khi * 8;
    const unsigned short* ar2 = A2 + (size_t)(row0 + rlo) * D + khi * 8;

    f32x4 acc[8] = {};
    #pragma unroll
    for (int q = 0; q < 8; ++q) {
        const unsigned short* ap = (q < 4) ? ar1 : ar2;
        short8 a = *(const short8*)(ap + (q & 3) * 32);
        #pragma unroll
        for (int c = 0; c < 8; ++c) {
            short8 b = *(const short8*)(Wp + ((q * 8 + c) * 64 + l) * 4);
            acc[c] = __builtin_amdgcn_mfma_f32_16x16x32_bf16(a, b, acc[c], 0, 0, 0);
        }
    }

    // stage accumulators to LDS: row=(l>>4)*4+j, col=c*16+(l&15)
    #pragma unroll
    for (int c = 0; c < 8; ++c)
        #pragma unroll
        for (int j = 0; j < 4; ++j)
            s[w][khi * 4 + j][c * 16 + rlo] = acc[c][j];
    __syncthreads();

    int r = l >> 2, c0 = (l & 3) * 32;
    const float* srow = &s[w][r][c0];
    size_t grow = (size_t)(blockIdx.x * 64 + w * 16 + r);
    if (do_relu) {   // layer 1: bias + relu + bf16 pack
        #pragma unroll
        for (int i = 0; i < 4; ++i) {
            float4 u = *(const float4*)(srow + i * 8);
            float4 v = *(const float4*)(srow + i * 8 + 4);
            float4 ba = *(const float4*)(bias + c0 + i * 8);
            float4 bb = *(const float4*)(bias + c0 + i * 8 + 4);
            float f0 = fmaxf(u.x + ba.x, 0.f), f1 = fmaxf(u.y + ba.y, 0.f);
            float f2 = fmaxf(u.z + ba.z, 0.f), f3 = fmaxf(u.w + ba.w, 0.f);
            float f4 = fmaxf(v.x + bb.x, 0.f), f5 = fmaxf(v.y + bb.y, 0.f);
            float f6 = fmaxf(v.z + bb.z, 0.f), f7 = fmaxf(v.w + bb.w, 0.f);
            uint4 o;
            o.x = f2bf(f0) | ((unsigned)f2bf(f1) << 16);
            o.y = f2bf(f2) | ((unsigned)f2bf(f3) << 16);
            o.z = f2bf(f4) | ((unsigned)f2bf(f5) << 16);
            o.w = f2bf(f6) | ((unsigned)f2bf(f7) << 16);
            *(uint4*)(outb + grow * D + c0 + i * 8) = o;
        }
    } else {         // layer 2: bias + f32 store
        #pragma unroll
        for (int i = 0; i < 8; ++i) {
            float4 u = *(const float4*)(srow + i * 4);
            float4 ba = *(const float4*)(bias + c0 + i * 4);
            float4 o = {u.x + ba.x, u.y + ba.y, u.z + ba.z, u.w + ba.w};
            *(float4*)(outf + grow * D + c0 + i * 4) = o;
        }
    }
}

// ---------------- launch ----------------

extern "C" void kernel_launch(void* const* d_in, const int* in_sizes, int n_in,
                              void* d_out, int out_size, void* d_ws, size_t ws_size,
                              hipStream_t stream) {
    const float* x       = (const float*)d_in[0];
    const int*   src     = (const int*)d_in[1];
    const int*   dst     = (const int*)d_in[2];
    const float* W_self1 = (const float*)d_in[3];
    const float* W_neigh1= (const float*)d_in[4];
    const float* b1      = (const float*)d_in[5];
    const float* W_self2 = (const float*)d_in[6];
    const float* W_neigh2= (const float*)d_in[7];
    const float* b2      = (const float*)d_in[8];
    float* out = (float*)d_out;

    char* ws = (char*)d_ws;
    size_t off_deg  = 0;                        // 40000 int
    size_t off_rs   = off_deg  + 160000;        // 40001 int
    size_t off_cur  = off_rs   + 160016;        // 40000 int
    size_t off_es   = off_cur  + 160000;        // 640000 int
    size_t off_xb   = off_es   + 2560000;       // 40000*128 bf16
    size_t off_h1b  = off_xb   + 10240000;      // 40000*128 bf16
    size_t off_mb   = off_h1b  + 10240000;      // 40000*128 bf16
    size_t off_wp   = off_mb   + 10240000;      // 2*16384 uint
    size_t off_bs   = off_wp   + 131072;        // 157 int
    size_t total    = off_bs   + 640;
    if (ws_size < total) return;

    int* deg       = (int*)(ws + off_deg);
    int* row_start = (int*)(ws + off_rs);
    int* cursor    = (int*)(ws + off_cur);
    int* edge_src  = (int*)(ws + off_es);
    unsigned short* xb   = (unsigned short*)(ws + off_xb);
    unsigned short* h1b  = (unsigned short*)(ws + off_h1b);
    unsigned short* mb   = (unsigned short*)(ws + off_mb);
    unsigned* Wp         = (unsigned*)(ws + off_wp);
    int* block_sums      = (int*)(ws + off_bs);

    hipMemsetAsync(deg, 0, 160000, stream);

    // CSR build
    count_deg<<<(N_EDGES + 255) / 256, 256, 0, stream>>>(dst, deg);
    scan_phase1<<<SCAN_NBLK, 256, 0, stream>>>(deg, row_start, block_sums);
    scan_phase2<<<1, 256, 0, stream>>>(block_sums, row_start);
    scan_phase3<<<SCAN_NBLK, 256, 0, stream>>>(block_sums, row_start, cursor);
    fill_edges<<<(N_EDGES + 255) / 256, 256, 0, stream>>>(src, dst, cursor, edge_src);

    // bf16 plane + weight pack
    f32_to_bf16<<<2500, 256, 0, stream>>>(x, xb);                     // 640000 thr
    pack_W<<<128, 256, 0, stream>>>(W_self1, W_neigh1, W_self2, W_neigh2, Wp);

    // layer 1
    agg_mean_bf16<<<N_NODES / 4, 256, 0, stream>>>(xb, row_start, edge_src, mb);
    gemm_mfma<<<N_NODES / 64, 256, 0, stream>>>(xb, mb, Wp, b1, h1b, nullptr, 1);

    // layer 2
    agg_mean_bf16<<<N_NODES / 4, 256, 0, stream>>>(h1b, row_start, edge_src, mb);
    gemm_mfma<<<N_NODES / 64, 256, 0, stream>>>(h1b, mb, Wp + 16384, b2, nullptr, out, 0);
}

// Round 4
// 168.185 us; speedup vs baseline: 1.9891x; 1.1437x over previous
//
#include <hip/hip_runtime.h>

#define N_NODES 40000
#define N_EDGES 640000
#define D 128

typedef __attribute__((ext_vector_type(8))) short short8;   // 8 bf16 = 4 VGPR
typedef __attribute__((ext_vector_type(4))) float f32x4;

__device__ __forceinline__ unsigned short f2bf(float f) {
    unsigned u = __float_as_uint(f);
    unsigned r = u + 0x7FFF + ((u >> 16) & 1);   // round-to-nearest-even
    return (unsigned short)(r >> 16);
}

// ---------------- fused prep: zero deg, x->bf16, weight pack ----------------
// grid 2500 x 256 = 640000 threads

__global__ __launch_bounds__(256) void prep(
    const float* __restrict__ x, unsigned short* __restrict__ xb,
    const float* __restrict__ Ws1, const float* __restrict__ Wn1,
    const float* __restrict__ Ws2, const float* __restrict__ Wn2,
    unsigned* __restrict__ Wp, int* __restrict__ deg) {
    int t = blockIdx.x * 256 + threadIdx.x;

    // zero degree counters
    if (t < N_NODES) deg[t] = 0;

    // fp32 -> bf16 feature plane (8 elems/thread)
    {
        float4 a = ((const float4*)x)[t * 2];
        float4 b = ((const float4*)x)[t * 2 + 1];
        uint4 o;
        o.x = f2bf(a.x) | ((unsigned)f2bf(a.y) << 16);
        o.y = f2bf(a.z) | ((unsigned)f2bf(a.w) << 16);
        o.z = f2bf(b.x) | ((unsigned)f2bf(b.y) << 16);
        o.w = f2bf(b.z) | ((unsigned)f2bf(b.w) << 16);
        ((uint4*)xb)[t] = o;
    }

    // weight pre-pack into MFMA B-fragment order:
    // element (((q*8+c)*64+l)*8 + j) = W[(q&3)*32 + (l>>4)*8 + j][c*16 + (l&15)]
    if (t < 32768) {
        int L   = t >> 14;
        int rem = t & 16383;
        int j2 = rem & 3;
        int l  = (rem >> 2) & 63;
        int c  = (rem >> 8) & 7;
        int q  = rem >> 11;
        const float* W = (L == 0) ? (q < 4 ? Ws1 : Wn1) : (q < 4 ? Ws2 : Wn2);
        int k0  = (q & 3) * 32 + (l >> 4) * 8 + 2 * j2;
        int col = c * 16 + (l & 15);
        float v0 = W[(size_t)k0 * D + col];
        float v1 = W[(size_t)(k0 + 1) * D + col];
        Wp[t] = f2bf(v0) | ((unsigned)f2bf(v1) << 16);
    }
}

// ---------------- CSR build ----------------

__global__ void count_deg(const int* __restrict__ dst, int* __restrict__ deg) {
    int e = blockIdx.x * 256 + threadIdx.x;
    if (e < N_EDGES) atomicAdd(&deg[dst[e]], 1);
}

#define SCAN_CHUNK 256
#define SCAN_NBLK ((N_NODES + SCAN_CHUNK - 1) / SCAN_CHUNK)  // 157

__global__ __launch_bounds__(256) void scan_phase1(
    const int* __restrict__ deg, int* __restrict__ row_start,
    int* __restrict__ block_sums) {
    __shared__ int s[SCAN_CHUNK];
    int t = threadIdx.x;
    int i = blockIdx.x * SCAN_CHUNK + t;
    int v = (i < N_NODES) ? deg[i] : 0;
    s[t] = v;
    __syncthreads();
    for (int off = 1; off < SCAN_CHUNK; off <<= 1) {
        int u = 0;
        if (t >= off) u = s[t - off];
        __syncthreads();
        if (t >= off) s[t] += u;
        __syncthreads();
    }
    if (i < N_NODES) row_start[i] = s[t] - v;
    if (t == SCAN_CHUNK - 1) block_sums[blockIdx.x] = s[t];
}

__global__ __launch_bounds__(256) void scan_phase2(
    int* __restrict__ block_sums, int* __restrict__ row_start) {
    __shared__ int s[256];
    int t = threadIdx.x;
    int v = (t < SCAN_NBLK) ? block_sums[t] : 0;
    s[t] = v;
    __syncthreads();
    for (int off = 1; off < 256; off <<= 1) {
        int u = 0;
        if (t >= off) u = s[t - off];
        __syncthreads();
        if (t >= off) s[t] += u;
        __syncthreads();
    }
    if (t < SCAN_NBLK) block_sums[t] = s[t] - v;
    if (t == SCAN_NBLK - 1) row_start[N_NODES] = s[t];
}

__global__ __launch_bounds__(256) void scan_phase3(
    const int* __restrict__ block_sums, int* __restrict__ row_start,
    int* __restrict__ cursor) {
    int i = blockIdx.x * SCAN_CHUNK + threadIdx.x;
    if (i < N_NODES) {
        int v = row_start[i] + block_sums[blockIdx.x];
        row_start[i] = v;
        cursor[i] = v;
    }
}

__global__ void fill_edges(const int* __restrict__ src, const int* __restrict__ dst,
                           int* __restrict__ cursor, int* __restrict__ edge_src) {
    int e = blockIdx.x * 256 + threadIdx.x;
    if (e < N_EDGES) {
        int p = atomicAdd(&cursor[dst[e]], 1);
        edge_src[p] = src[e];
    }
}

// ---------------- mean aggregation: deep-MLP bf16 gather ----------------
// one wave per node, 1 dword (2 feats) per lane -> whole 256 B row per load.
// 8 edges per iteration = 8 independent row loads in flight.

__global__ __launch_bounds__(512) void agg_mean_bf16(
    const unsigned short* __restrict__ hb, const int* __restrict__ row_start,
    const int* __restrict__ edge_src, unsigned short* __restrict__ mean_out) {
    int wave = threadIdx.x >> 6;
    int lane = threadIdx.x & 63;
    int n = blockIdx.x * 8 + wave;
    if (n >= N_NODES) return;
    int e0 = row_start[n], e1 = row_start[n + 1];
    const unsigned* h4 = (const unsigned*)hb;   // 64 dwords per row
    float a0 = 0.f, a1 = 0.f;

    int e = e0;
    for (; e + 8 <= e1; e += 8) {
        int s0 = edge_src[e + 0], s1 = edge_src[e + 1];
        int s2 = edge_src[e + 2], s3 = edge_src[e + 3];
        int s4 = edge_src[e + 4], s5 = edge_src[e + 5];
        int s6 = edge_src[e + 6], s7 = edge_src[e + 7];
        unsigned u0 = h4[(size_t)s0 * 64 + lane];
        unsigned u1 = h4[(size_t)s1 * 64 + lane];
        unsigned u2 = h4[(size_t)s2 * 64 + lane];
        unsigned u3 = h4[(size_t)s3 * 64 + lane];
        unsigned u4 = h4[(size_t)s4 * 64 + lane];
        unsigned u5 = h4[(size_t)s5 * 64 + lane];
        unsigned u6 = h4[(size_t)s6 * 64 + lane];
        unsigned u7 = h4[(size_t)s7 * 64 + lane];
        a0 += __uint_as_float(u0 << 16) + __uint_as_float(u1 << 16)
            + __uint_as_float(u2 << 16) + __uint_as_float(u3 << 16)
            + __uint_as_float(u4 << 16) + __uint_as_float(u5 << 16)
            + __uint_as_float(u6 << 16) + __uint_as_float(u7 << 16);
        a1 += __uint_as_float(u0 & 0xFFFF0000u) + __uint_as_float(u1 & 0xFFFF0000u)
            + __uint_as_float(u2 & 0xFFFF0000u) + __uint_as_float(u3 & 0xFFFF0000u)
            + __uint_as_float(u4 & 0xFFFF0000u) + __uint_as_float(u5 & 0xFFFF0000u)
            + __uint_as_float(u6 & 0xFFFF0000u) + __uint_as_float(u7 & 0xFFFF0000u);
    }
    if (e < e1) {   // predicated 8-wide tail: all loads issue in parallel
        int last = e1 - 1;
        int i0 = e,     i1 = min(e + 1, last), i2 = min(e + 2, last), i3 = min(e + 3, last);
        int i4 = min(e + 4, last), i5 = min(e + 5, last), i6 = min(e + 6, last), i7 = min(e + 7, last);
        int s0 = edge_src[i0], s1 = edge_src[i1], s2 = edge_src[i2], s3 = edge_src[i3];
        int s4 = edge_src[i4], s5 = edge_src[i5], s6 = edge_src[i6], s7 = edge_src[i7];
        unsigned u0 = h4[(size_t)s0 * 64 + lane];
        unsigned u1 = h4[(size_t)s1 * 64 + lane];
        unsigned u2 = h4[(size_t)s2 * 64 + lane];
        unsigned u3 = h4[(size_t)s3 * 64 + lane];
        unsigned u4 = h4[(size_t)s4 * 64 + lane];
        unsigned u5 = h4[(size_t)s5 * 64 + lane];
        unsigned u6 = h4[(size_t)s6 * 64 + lane];
        unsigned u7 = h4[(size_t)s7 * 64 + lane];
        int r = e1 - e;   // 1..8 valid
        a0 += __uint_as_float(u0 << 16);
        a1 += __uint_as_float(u0 & 0xFFFF0000u);
        if (r > 1) { a0 += __uint_as_float(u1 << 16); a1 += __uint_as_float(u1 & 0xFFFF0000u); }
        if (r > 2) { a0 += __uint_as_float(u2 << 16); a1 += __uint_as_float(u2 & 0xFFFF0000u); }
        if (r > 3) { a0 += __uint_as_float(u3 << 16); a1 += __uint_as_float(u3 & 0xFFFF0000u); }
        if (r > 4) { a0 += __uint_as_float(u4 << 16); a1 += __uint_as_float(u4 & 0xFFFF0000u); }
        if (r > 5) { a0 += __uint_as_float(u5 << 16); a1 += __uint_as_float(u5 & 0xFFFF0000u); }
        if (r > 6) { a0 += __uint_as_float(u6 << 16); a1 += __uint_as_float(u6 & 0xFFFF0000u); }
        if (r > 7) { a0 += __uint_as_float(u7 << 16); a1 += __uint_as_float(u7 & 0xFFFF0000u); }
    }

    float cnt = (float)(e1 - e0);
    float inv = cnt > 0.f ? 1.0f / cnt : 0.f;
    unsigned o = f2bf(a0 * inv) | ((unsigned)f2bf(a1 * inv) << 16);
    ((unsigned*)mean_out)[(size_t)n * 64 + lane] = o;
}

// ---------------- bf16 MFMA dual GEMM ----------------

__global__ __launch_bounds__(256) void gemm_mfma(
    const unsigned short* __restrict__ A1, const unsigned short* __restrict__ A2,
    const unsigned* __restrict__ Wp,      // 16384 uints, fragment order
    const float* __restrict__ bias,
    unsigned short* __restrict__ outb,    // bf16 out (layer 1) or nullptr
    float* __restrict__ outf,             // f32 out (layer 2) or nullptr
    int do_relu) {
    __shared__ float s[4][16][132];       // +4 pad
    int tid = threadIdx.x;
    int w = tid >> 6, l = tid & 63;
    int rlo = l & 15, khi = l >> 4;
    int row0 = blockIdx.x * 64 + w * 16;

    const unsigned short* ar1 = A1 + (size_t)(row0 + rlo) * D + khi * 8;
    const unsigned short* ar2 = A2 + (size_t)(row0 + rlo) * D + khi * 8;

    f32x4 acc[8] = {};
    #pragma unroll
    for (int q = 0; q < 8; ++q) {
        const unsigned short* ap = (q < 4) ? ar1 : ar2;
        short8 a = *(const short8*)(ap + (q & 3) * 32);
        #pragma unroll
        for (int c = 0; c < 8; ++c) {
            short8 b = *(const short8*)(Wp + ((q * 8 + c) * 64 + l) * 4);
            acc[c] = __builtin_amdgcn_mfma_f32_16x16x32_bf16(a, b, acc[c], 0, 0, 0);
        }
    }

    #pragma unroll
    for (int c = 0; c < 8; ++c)
        #pragma unroll
        for (int j = 0; j < 4; ++j)
            s[w][khi * 4 + j][c * 16 + rlo] = acc[c][j];
    __syncthreads();

    int r = l >> 2, c0 = (l & 3) * 32;
    const float* srow = &s[w][r][c0];
    size_t grow = (size_t)(blockIdx.x * 64 + w * 16 + r);
    if (do_relu) {
        #pragma unroll
        for (int i = 0; i < 4; ++i) {
            float4 u = *(const float4*)(srow + i * 8);
            float4 v = *(const float4*)(srow + i * 8 + 4);
            float4 ba = *(const float4*)(bias + c0 + i * 8);
            float4 bb = *(const float4*)(bias + c0 + i * 8 + 4);
            float f0 = fmaxf(u.x + ba.x, 0.f), f1 = fmaxf(u.y + ba.y, 0.f);
            float f2 = fmaxf(u.z + ba.z, 0.f), f3 = fmaxf(u.w + ba.w, 0.f);
            float f4 = fmaxf(v.x + bb.x, 0.f), f5 = fmaxf(v.y + bb.y, 0.f);
            float f6 = fmaxf(v.z + bb.z, 0.f), f7 = fmaxf(v.w + bb.w, 0.f);
            uint4 o;
            o.x = f2bf(f0) | ((unsigned)f2bf(f1) << 16);
            o.y = f2bf(f2) | ((unsigned)f2bf(f3) << 16);
            o.z = f2bf(f4) | ((unsigned)f2bf(f5) << 16);
            o.w = f2bf(f6) | ((unsigned)f2bf(f7) << 16);
            *(uint4*)(outb + grow * D + c0 + i * 8) = o;
        }
    } else {
        #pragma unroll
        for (int i = 0; i < 8; ++i) {
            float4 u = *(const float4*)(srow + i * 4);
            float4 ba = *(const float4*)(bias + c0 + i * 4);
            float4 o = {u.x + ba.x, u.y + ba.y, u.z + ba.z, u.w + ba.w};
            *(float4*)(outf + grow * D + c0 + i * 4) = o;
        }
    }
}

// ---------------- launch ----------------

extern "C" void kernel_launch(void* const* d_in, const int* in_sizes, int n_in,
                              void* d_out, int out_size, void* d_ws, size_t ws_size,
                              hipStream_t stream) {
    const float* x       = (const float*)d_in[0];
    const int*   src     = (const int*)d_in[1];
    const int*   dst     = (const int*)d_in[2];
    const float* W_self1 = (const float*)d_in[3];
    const float* W_neigh1= (const float*)d_in[4];
    const float* b1      = (const float*)d_in[5];
    const float* W_self2 = (const float*)d_in[6];
    const float* W_neigh2= (const float*)d_in[7];
    const float* b2      = (const float*)d_in[8];
    float* out = (float*)d_out;

    char* ws = (char*)d_ws;
    size_t off_deg  = 0;                        // 40000 int
    size_t off_rs   = off_deg  + 160000;        // 40001 int
    size_t off_cur  = off_rs   + 160016;        // 40000 int
    size_t off_es   = off_cur  + 160000;        // 640000 int
    size_t off_xb   = off_es   + 2560000;       // 40000*128 bf16
    size_t off_h1b  = off_xb   + 10240000;      // 40000*128 bf16
    size_t off_mb   = off_h1b  + 10240000;      // 40000*128 bf16
    size_t off_wp   = off_mb   + 10240000;      // 2*16384 uint
    size_t off_bs   = off_wp   + 131072;        // 157 int
    size_t total    = off_bs   + 640;
    if (ws_size < total) return;

    int* deg       = (int*)(ws + off_deg);
    int* row_start = (int*)(ws + off_rs);
    int* cursor    = (int*)(ws + off_cur);
    int* edge_src  = (int*)(ws + off_es);
    unsigned short* xb   = (unsigned short*)(ws + off_xb);
    unsigned short* h1b  = (unsigned short*)(ws + off_h1b);
    unsigned short* mb   = (unsigned short*)(ws + off_mb);
    unsigned* Wp         = (unsigned*)(ws + off_wp);
    int* block_sums      = (int*)(ws + off_bs);

    // prep (deg zero + cvt + pack) then CSR build
    prep<<<2500, 256, 0, stream>>>(x, xb, W_self1, W_neigh1, W_self2, W_neigh2, Wp, deg);
    count_deg<<<(N_EDGES + 255) / 256, 256, 0, stream>>>(dst, deg);
    scan_phase1<<<SCAN_NBLK, 256, 0, stream>>>(deg, row_start, block_sums);
    scan_phase2<<<1, 256, 0, stream>>>(block_sums, row_start);
    scan_phase3<<<SCAN_NBLK, 256, 0, stream>>>(block_sums, row_start, cursor);
    fill_edges<<<(N_EDGES + 255) / 256, 256, 0, stream>>>(src, dst, cursor, edge_src);

    // layer 1
    agg_mean_bf16<<<N_NODES / 8, 512, 0, stream>>>(xb, row_start, edge_src, mb);
    gemm_mfma<<<N_NODES / 64, 256, 0, stream>>>(xb, mb, Wp, b1, h1b, nullptr, 1);

    // layer 2
    agg_mean_bf16<<<N_NODES / 8, 512, 0, stream>>>(h1b, row_start, edge_src, mb);
    gemm_mfma<<<N_NODES / 64, 256, 0, stream>>>(h1b, mb, Wp + 16384, b2, nullptr, out, 0);
}

// Round 5
// 153.899 us; speedup vs baseline: 2.1738x; 1.0928x over previous
//
#include <hip/hip_runtime.h>

#define N_NODES 40000
#define N_EDGES 640000
#define D 128

typedef __attribute__((ext_vector_type(8))) short short8;   // 8 bf16 = 4 VGPR
typedef __attribute__((ext_vector_type(4))) float f32x4;

__device__ __forceinline__ unsigned short f2bf(float f) {
    unsigned u = __float_as_uint(f);
    unsigned r = u + 0x7FFF + ((u >> 16) & 1);   // round-to-nearest-even
    return (unsigned short)(r >> 16);
}

// ---------------- fused prep: x->bf16, weight pack, degree count ------------
// grid 2500 x 256 = 640000 threads. deg must be zeroed beforehand (memset).

__global__ __launch_bounds__(256) void prep_count(
    const float* __restrict__ x, unsigned short* __restrict__ xb,
    const float* __restrict__ Ws1, const float* __restrict__ Wn1,
    const float* __restrict__ Ws2, const float* __restrict__ Wn2,
    unsigned* __restrict__ Wp, const int* __restrict__ dst,
    int* __restrict__ deg) {
    int t = blockIdx.x * 256 + threadIdx.x;

    // fp32 -> bf16 feature plane (8 elems/thread)
    {
        float4 a = ((const float4*)x)[t * 2];
        float4 b = ((const float4*)x)[t * 2 + 1];
        uint4 o;
        o.x = f2bf(a.x) | ((unsigned)f2bf(a.y) << 16);
        o.y = f2bf(a.z) | ((unsigned)f2bf(a.w) << 16);
        o.z = f2bf(b.x) | ((unsigned)f2bf(b.y) << 16);
        o.w = f2bf(b.z) | ((unsigned)f2bf(b.w) << 16);
        ((uint4*)xb)[t] = o;
    }

    // degree count (1 edge/thread)
    atomicAdd(&deg[dst[t]], 1);

    // weight pre-pack into MFMA B-fragment order:
    // element (((q*8+c)*64+l)*8 + j) = W[(q&3)*32 + (l>>4)*8 + j][c*16 + (l&15)]
    if (t < 32768) {
        int L   = t >> 14;
        int rem = t & 16383;
        int j2 = rem & 3;
        int l  = (rem >> 2) & 63;
        int c  = (rem >> 8) & 7;
        int q  = rem >> 11;
        const float* W = (L == 0) ? (q < 4 ? Ws1 : Wn1) : (q < 4 ? Ws2 : Wn2);
        int k0  = (q & 3) * 32 + (l >> 4) * 8 + 2 * j2;
        int col = c * 16 + (l & 15);
        float v0 = W[(size_t)k0 * D + col];
        float v1 = W[(size_t)(k0 + 1) * D + col];
        Wp[t] = f2bf(v0) | ((unsigned)f2bf(v1) << 16);
    }
}

// ---------------- CSR scan ----------------

#define SCAN_CHUNK 256
#define SCAN_NBLK ((N_NODES + SCAN_CHUNK - 1) / SCAN_CHUNK)  // 157

__global__ __launch_bounds__(256) void scan_phase1(
    const int* __restrict__ deg, int* __restrict__ row_start,
    int* __restrict__ block_sums) {
    __shared__ int s[SCAN_CHUNK];
    int t = threadIdx.x;
    int i = blockIdx.x * SCAN_CHUNK + t;
    int v = (i < N_NODES) ? deg[i] : 0;
    s[t] = v;
    __syncthreads();
    for (int off = 1; off < SCAN_CHUNK; off <<= 1) {
        int u = 0;
        if (t >= off) u = s[t - off];
        __syncthreads();
        if (t >= off) s[t] += u;
        __syncthreads();
    }
    if (i < N_NODES) row_start[i] = s[t] - v;
    if (t == SCAN_CHUNK - 1) block_sums[blockIdx.x] = s[t];
}

__global__ __launch_bounds__(256) void scan_phase2(
    int* __restrict__ block_sums, int* __restrict__ row_start) {
    __shared__ int s[256];
    int t = threadIdx.x;
    int v = (t < SCAN_NBLK) ? block_sums[t] : 0;
    s[t] = v;
    __syncthreads();
    for (int off = 1; off < 256; off <<= 1) {
        int u = 0;
        if (t >= off) u = s[t - off];
        __syncthreads();
        if (t >= off) s[t] += u;
        __syncthreads();
    }
    if (t < SCAN_NBLK) block_sums[t] = s[t] - v;
    if (t == SCAN_NBLK - 1) row_start[N_NODES] = s[t];
}

__global__ __launch_bounds__(256) void scan_phase3(
    const int* __restrict__ block_sums, int* __restrict__ row_start,
    int* __restrict__ cursor) {
    int i = blockIdx.x * SCAN_CHUNK + threadIdx.x;
    if (i < N_NODES) {
        int v = row_start[i] + block_sums[blockIdx.x];
        row_start[i] = v;
        cursor[i] = v;
    }
}

__global__ void fill_edges(const int* __restrict__ src, const int* __restrict__ dst,
                           int* __restrict__ cursor, int* __restrict__ edge_src) {
    int e = blockIdx.x * 256 + threadIdx.x;
    if (e < N_EDGES) {
        int p = atomicAdd(&cursor[dst[e]], 1);
        edge_src[p] = src[e];
    }
}

// ---------------- fused layer: mean-agg into LDS + dual MFMA GEMM -----------
// block = 64 nodes, 512 threads (8 waves).
// phase A: wave w aggregates nodes w*8..w*8+7 (8-edge-deep gather MLP) -> LDS
// phase B: wave w computes rows (w>>1)*16..+15, cols (w&1)*64..+63
//          self operand from global A, neigh operand from LDS mean tile
// phase C: stage acc to LDS, vectorized bias(+relu) epilogue

#define PADW 68   // dwords per mean row in LDS (64 data + 4 pad)

__global__ __launch_bounds__(512) void fused_layer(
    const unsigned short* __restrict__ A,     // input plane bf16 [N][128]
    const int* __restrict__ row_start,
    const int* __restrict__ edge_src,
    const unsigned* __restrict__ Wp,          // 16384 uints, fragment order
    const float* __restrict__ bias,
    unsigned short* __restrict__ outb,        // bf16 out (layer 1) or nullptr
    float* __restrict__ outf,                 // f32 out (layer 2) or nullptr
    int do_relu) {
    __shared__ float sf[64 * 132];            // 33792 B; phase A/B alias as mean
    unsigned* meanL = (unsigned*)sf;          // [64][PADW] dwords (2 bf16 each)

    int tid = threadIdx.x;
    int w = tid >> 6, l = tid & 63;
    int blk = blockIdx.x;
    const unsigned* h4 = (const unsigned*)A;  // 64 dwords per row

    // ---- phase A: aggregation ----
    for (int i = 0; i < 8; ++i) {
        int lr = w * 8 + i;
        int n = blk * 64 + lr;
        int e0 = row_start[n], e1 = row_start[n + 1];
        float a0 = 0.f, a1 = 0.f;
        int e = e0;
        for (; e + 8 <= e1; e += 8) {
            int s0 = edge_src[e + 0], s1 = edge_src[e + 1];
            int s2 = edge_src[e + 2], s3 = edge_src[e + 3];
            int s4 = edge_src[e + 4], s5 = edge_src[e + 5];
            int s6 = edge_src[e + 6], s7 = edge_src[e + 7];
            unsigned u0 = h4[(size_t)s0 * 64 + l];
            unsigned u1 = h4[(size_t)s1 * 64 + l];
            unsigned u2 = h4[(size_t)s2 * 64 + l];
            unsigned u3 = h4[(size_t)s3 * 64 + l];
            unsigned u4 = h4[(size_t)s4 * 64 + l];
            unsigned u5 = h4[(size_t)s5 * 64 + l];
            unsigned u6 = h4[(size_t)s6 * 64 + l];
            unsigned u7 = h4[(size_t)s7 * 64 + l];
            a0 += __uint_as_float(u0 << 16) + __uint_as_float(u1 << 16)
                + __uint_as_float(u2 << 16) + __uint_as_float(u3 << 16)
                + __uint_as_float(u4 << 16) + __uint_as_float(u5 << 16)
                + __uint_as_float(u6 << 16) + __uint_as_float(u7 << 16);
            a1 += __uint_as_float(u0 & 0xFFFF0000u) + __uint_as_float(u1 & 0xFFFF0000u)
                + __uint_as_float(u2 & 0xFFFF0000u) + __uint_as_float(u3 & 0xFFFF0000u)
                + __uint_as_float(u4 & 0xFFFF0000u) + __uint_as_float(u5 & 0xFFFF0000u)
                + __uint_as_float(u6 & 0xFFFF0000u) + __uint_as_float(u7 & 0xFFFF0000u);
        }
        if (e < e1) {   // predicated 8-wide tail
            int last = e1 - 1;
            int i1 = min(e + 1, last), i2 = min(e + 2, last), i3 = min(e + 3, last);
            int i4 = min(e + 4, last), i5 = min(e + 5, last), i6 = min(e + 6, last),
                i7 = min(e + 7, last);
            int s0 = edge_src[e],  s1 = edge_src[i1], s2 = edge_src[i2], s3 = edge_src[i3];
            int s4 = edge_src[i4], s5 = edge_src[i5], s6 = edge_src[i6], s7 = edge_src[i7];
            unsigned u0 = h4[(size_t)s0 * 64 + l];
            unsigned u1 = h4[(size_t)s1 * 64 + l];
            unsigned u2 = h4[(size_t)s2 * 64 + l];
            unsigned u3 = h4[(size_t)s3 * 64 + l];
            unsigned u4 = h4[(size_t)s4 * 64 + l];
            unsigned u5 = h4[(size_t)s5 * 64 + l];
            unsigned u6 = h4[(size_t)s6 * 64 + l];
            unsigned u7 = h4[(size_t)s7 * 64 + l];
            int r = e1 - e;
            a0 += __uint_as_float(u0 << 16);
            a1 += __uint_as_float(u0 & 0xFFFF0000u);
            if (r > 1) { a0 += __uint_as_float(u1 << 16); a1 += __uint_as_float(u1 & 0xFFFF0000u); }
            if (r > 2) { a0 += __uint_as_float(u2 << 16); a1 += __uint_as_float(u2 & 0xFFFF0000u); }
            if (r > 3) { a0 += __uint_as_float(u3 << 16); a1 += __uint_as_float(u3 & 0xFFFF0000u); }
            if (r > 4) { a0 += __uint_as_float(u4 << 16); a1 += __uint_as_float(u4 & 0xFFFF0000u); }
            if (r > 5) { a0 += __uint_as_float(u5 << 16); a1 += __uint_as_float(u5 & 0xFFFF0000u); }
            if (r > 6) { a0 += __uint_as_float(u6 << 16); a1 += __uint_as_float(u6 & 0xFFFF0000u); }
            if (r > 7) { a0 += __uint_as_float(u7 << 16); a1 += __uint_as_float(u7 & 0xFFFF0000u); }
        }
        float cnt = (float)(e1 - e0);
        float inv = cnt > 0.f ? 1.0f / cnt : 0.f;
        meanL[lr * PADW + l] = f2bf(a0 * inv) | ((unsigned)f2bf(a1 * inv) << 16);
    }

    // ---- phase B: dual GEMM ----
    int rlo = l & 15, khi = l >> 4;
    int row0g = blk * 64 + (w >> 1) * 16;
    const unsigned short* ar = A + (size_t)(row0g + rlo) * D + khi * 8;

    f32x4 acc[4] = {};
    // self half first: no LDS dependence -> runs before the barrier
    #pragma unroll
    for (int q = 0; q < 4; ++q) {
        short8 a = *(const short8*)(ar + q * 32);
        #pragma unroll
        for (int c = 0; c < 4; ++c) {
            int cg = (w & 1) * 4 + c;
            short8 b = *(const short8*)(Wp + ((q * 8 + cg) * 64 + l) * 4);
            acc[c] = __builtin_amdgcn_mfma_f32_16x16x32_bf16(a, b, acc[c], 0, 0, 0);
        }
    }
    __syncthreads();
    // neigh half from LDS mean tile
    int lr0 = (w >> 1) * 16 + rlo;
    #pragma unroll
    for (int q = 4; q < 8; ++q) {
        short8 a = *(const short8*)(meanL + lr0 * PADW + khi * 4 + (q & 3) * 16);
        #pragma unroll
        for (int c = 0; c < 4; ++c) {
            int cg = (w & 1) * 4 + c;
            short8 b = *(const short8*)(Wp + ((q * 8 + cg) * 64 + l) * 4);
            acc[c] = __builtin_amdgcn_mfma_f32_16x16x32_bf16(a, b, acc[c], 0, 0, 0);
        }
    }
    __syncthreads();   // all reads of meanL done before sf overwrite

    // ---- phase C: epilogue via LDS stage ----
    #pragma unroll
    for (int c = 0; c < 4; ++c) {
        int cg = (w & 1) * 4 + c;
        #pragma unroll
        for (int j = 0; j < 4; ++j)
            sf[((w >> 1) * 16 + khi * 4 + j) * 132 + cg * 16 + rlo] = acc[c][j];
    }
    __syncthreads();

    int row = tid >> 3, c0 = (tid & 7) * 16;
    const float* srow = &sf[row * 132 + c0];
    float4 u0 = *(const float4*)(srow + 0);
    float4 u1 = *(const float4*)(srow + 4);
    float4 u2 = *(const float4*)(srow + 8);
    float4 u3 = *(const float4*)(srow + 12);
    float4 b0 = *(const float4*)(bias + c0 + 0);
    float4 b1 = *(const float4*)(bias + c0 + 4);
    float4 b2 = *(const float4*)(bias + c0 + 8);
    float4 b3 = *(const float4*)(bias + c0 + 12);
    size_t grow = (size_t)blk * 64 + row;
    if (do_relu) {
        float f0 = fmaxf(u0.x + b0.x, 0.f), f1 = fmaxf(u0.y + b0.y, 0.f);
        float f2 = fmaxf(u0.z + b0.z, 0.f), f3 = fmaxf(u0.w + b0.w, 0.f);
        float f4 = fmaxf(u1.x + b1.x, 0.f), f5 = fmaxf(u1.y + b1.y, 0.f);
        float f6 = fmaxf(u1.z + b1.z, 0.f), f7 = fmaxf(u1.w + b1.w, 0.f);
        float g0 = fmaxf(u2.x + b2.x, 0.f), g1 = fmaxf(u2.y + b2.y, 0.f);
        float g2 = fmaxf(u2.z + b2.z, 0.f), g3 = fmaxf(u2.w + b2.w, 0.f);
        float g4 = fmaxf(u3.x + b3.x, 0.f), g5 = fmaxf(u3.y + b3.y, 0.f);
        float g6 = fmaxf(u3.z + b3.z, 0.f), g7 = fmaxf(u3.w + b3.w, 0.f);
        uint4 o0, o1;
        o0.x = f2bf(f0) | ((unsigned)f2bf(f1) << 16);
        o0.y = f2bf(f2) | ((unsigned)f2bf(f3) << 16);
        o0.z = f2bf(f4) | ((unsigned)f2bf(f5) << 16);
        o0.w = f2bf(f6) | ((unsigned)f2bf(f7) << 16);
        o1.x = f2bf(g0) | ((unsigned)f2bf(g1) << 16);
        o1.y = f2bf(g2) | ((unsigned)f2bf(g3) << 16);
        o1.z = f2bf(g4) | ((unsigned)f2bf(g5) << 16);
        o1.w = f2bf(g6) | ((unsigned)f2bf(g7) << 16);
        *(uint4*)(outb + grow * D + c0 + 0) = o0;
        *(uint4*)(outb + grow * D + c0 + 8) = o1;
    } else {
        float4 o0 = {u0.x + b0.x, u0.y + b0.y, u0.z + b0.z, u0.w + b0.w};
        float4 o1 = {u1.x + b1.x, u1.y + b1.y, u1.z + b1.z, u1.w + b1.w};
        float4 o2 = {u2.x + b2.x, u2.y + b2.y, u2.z + b2.z, u2.w + b2.w};
        float4 o3 = {u3.x + b3.x, u3.y + b3.y, u3.z + b3.z, u3.w + b3.w};
        *(float4*)(outf + grow * D + c0 + 0)  = o0;
        *(float4*)(outf + grow * D + c0 + 4)  = o1;
        *(float4*)(outf + grow * D + c0 + 8)  = o2;
        *(float4*)(outf + grow * D + c0 + 12) = o3;
    }
}

// ---------------- launch ----------------

extern "C" void kernel_launch(void* const* d_in, const int* in_sizes, int n_in,
                              void* d_out, int out_size, void* d_ws, size_t ws_size,
                              hipStream_t stream) {
    const float* x       = (const float*)d_in[0];
    const int*   src     = (const int*)d_in[1];
    const int*   dst     = (const int*)d_in[2];
    const float* W_self1 = (const float*)d_in[3];
    const float* W_neigh1= (const float*)d_in[4];
    const float* b1      = (const float*)d_in[5];
    const float* W_self2 = (const float*)d_in[6];
    const float* W_neigh2= (const float*)d_in[7];
    const float* b2      = (const float*)d_in[8];
    float* out = (float*)d_out;

    char* ws = (char*)d_ws;
    size_t off_deg  = 0;                        // 40000 int
    size_t off_rs   = off_deg  + 160000;        // 40001 int
    size_t off_cur  = off_rs   + 160016;        // 40000 int
    size_t off_es   = off_cur  + 160000;        // 640000 int
    size_t off_xb   = off_es   + 2560000;       // 40000*128 bf16
    size_t off_h1b  = off_xb   + 10240000;      // 40000*128 bf16
    size_t off_wp   = off_h1b  + 10240000;      // 2*16384 uint
    size_t off_bs   = off_wp   + 131072;        // 157 int
    size_t total    = off_bs   + 640;
    if (ws_size < total) return;

    int* deg       = (int*)(ws + off_deg);
    int* row_start = (int*)(ws + off_rs);
    int* cursor    = (int*)(ws + off_cur);
    int* edge_src  = (int*)(ws + off_es);
    unsigned short* xb   = (unsigned short*)(ws + off_xb);
    unsigned short* h1b  = (unsigned short*)(ws + off_h1b);
    unsigned* Wp         = (unsigned*)(ws + off_wp);
    int* block_sums      = (int*)(ws + off_bs);

    hipMemsetAsync(deg, 0, 160000, stream);
    prep_count<<<2500, 256, 0, stream>>>(x, xb, W_self1, W_neigh1, W_self2,
                                         W_neigh2, Wp, dst, deg);
    scan_phase1<<<SCAN_NBLK, 256, 0, stream>>>(deg, row_start, block_sums);
    scan_phase2<<<1, 256, 0, stream>>>(block_sums, row_start);
    scan_phase3<<<SCAN_NBLK, 256, 0, stream>>>(block_sums, row_start, cursor);
    fill_edges<<<(N_EDGES + 255) / 256, 256, 0, stream>>>(src, dst, cursor, edge_src);

    fused_layer<<<N_NODES / 64, 512, 0, stream>>>(xb, row_start, edge_src,
                                                  Wp, b1, h1b, nullptr, 1);
    fused_layer<<<N_NODES / 64, 512, 0, stream>>>(h1b, row_start, edge_src,
                                                  Wp + 16384, b2, nullptr, out, 0);
}

// Round 6
// 145.002 us; speedup vs baseline: 2.3071x; 1.0614x over previous
//
#include <hip/hip_runtime.h>

#define N_NODES 40000
#define N_EDGES 640000
#define D 128
#define ES_CAP 1280000   // padded edge capacity: 640000 + 40000*15 = 1.24M max

typedef __attribute__((ext_vector_type(8))) short short8;   // 8 bf16 = 4 VGPR
typedef __attribute__((ext_vector_type(4))) float f32x4;

__device__ __forceinline__ unsigned short f2bf(float f) {
    unsigned u = __float_as_uint(f);
    unsigned r = u + 0x7FFF + ((u >> 16) & 1);   // round-to-nearest-even
    return (unsigned short)(r >> 16);
}

#define BF_LO(u) __uint_as_float((u) << 16)
#define BF_HI(u) __uint_as_float((u) & 0xFFFF0000u)

// ---------------- fused prep: x->bf16, weight pack, degree count, ----------
// ---------------- edge_src sentinel fill, zero pad-rows ---------------------
// grid 2500 x 256 = 640000 threads. deg must be zeroed beforehand (memset).

__global__ __launch_bounds__(256) void prep_count(
    const float* __restrict__ x, unsigned short* __restrict__ xb,
    unsigned short* __restrict__ h1b,
    const float* __restrict__ Ws1, const float* __restrict__ Wn1,
    const float* __restrict__ Ws2, const float* __restrict__ Wn2,
    unsigned* __restrict__ Wp, const int* __restrict__ dst,
    int* __restrict__ deg, int* __restrict__ edge_src) {
    int t = blockIdx.x * 256 + threadIdx.x;

    // sentinel-fill padded edge array (2 slots/thread covers ES_CAP)
    edge_src[t] = N_NODES;
    edge_src[t + 640000] = N_NODES;

    // zero the sentinel row of both feature planes (row N_NODES)
    if (t < 64) {
        ((unsigned*)xb)[N_NODES * 64 + t] = 0;
        ((unsigned*)h1b)[N_NODES * 64 + t] = 0;
    }

    // fp32 -> bf16 feature plane (8 elems/thread)
    {
        float4 a = ((const float4*)x)[t * 2];
        float4 b = ((const float4*)x)[t * 2 + 1];
        uint4 o;
        o.x = f2bf(a.x) | ((unsigned)f2bf(a.y) << 16);
        o.y = f2bf(a.z) | ((unsigned)f2bf(a.w) << 16);
        o.z = f2bf(b.x) | ((unsigned)f2bf(b.y) << 16);
        o.w = f2bf(b.z) | ((unsigned)f2bf(b.w) << 16);
        ((uint4*)xb)[t] = o;
    }

    // degree count (1 edge/thread)
    atomicAdd(&deg[dst[t]], 1);

    // weight pre-pack into MFMA B-fragment order:
    // element (((q*8+c)*64+l)*8 + j) = W[(q&3)*32 + (l>>4)*8 + j][c*16 + (l&15)]
    if (t < 32768) {
        int L   = t >> 14;
        int rem = t & 16383;
        int j2 = rem & 3;
        int l  = (rem >> 2) & 63;
        int c  = (rem >> 8) & 7;
        int q  = rem >> 11;
        const float* W = (L == 0) ? (q < 4 ? Ws1 : Wn1) : (q < 4 ? Ws2 : Wn2);
        int k0  = (q & 3) * 32 + (l >> 4) * 8 + 2 * j2;
        int col = c * 16 + (l & 15);
        float v0 = W[(size_t)k0 * D + col];
        float v1 = W[(size_t)(k0 + 1) * D + col];
        Wp[t] = f2bf(v0) | ((unsigned)f2bf(v1) << 16);
    }
}

// ---------------- CSR scan over PADDED degrees ------------------------------

#define SCAN_CHUNK 256
#define SCAN_NBLK ((N_NODES + SCAN_CHUNK - 1) / SCAN_CHUNK)  // 157

__global__ __launch_bounds__(256) void scan_phase1(
    const int* __restrict__ deg, int* __restrict__ row_start,
    int* __restrict__ block_sums) {
    __shared__ int s[SCAN_CHUNK];
    int t = threadIdx.x;
    int i = blockIdx.x * SCAN_CHUNK + t;
    int v = (i < N_NODES) ? ((deg[i] + 15) & ~15) : 0;   // padded degree
    s[t] = v;
    __syncthreads();
    for (int off = 1; off < SCAN_CHUNK; off <<= 1) {
        int u = 0;
        if (t >= off) u = s[t - off];
        __syncthreads();
        if (t >= off) s[t] += u;
        __syncthreads();
    }
    if (i < N_NODES) row_start[i] = s[t] - v;
    if (t == SCAN_CHUNK - 1) block_sums[blockIdx.x] = s[t];
}

__global__ __launch_bounds__(256) void scan_phase2(
    int* __restrict__ block_sums, int* __restrict__ row_start) {
    __shared__ int s[256];
    int t = threadIdx.x;
    int v = (t < SCAN_NBLK) ? block_sums[t] : 0;
    s[t] = v;
    __syncthreads();
    for (int off = 1; off < 256; off <<= 1) {
        int u = 0;
        if (t >= off) u = s[t - off];
        __syncthreads();
        if (t >= off) s[t] += u;
        __syncthreads();
    }
    if (t < SCAN_NBLK) block_sums[t] = s[t] - v;
    if (t == SCAN_NBLK - 1) row_start[N_NODES] = s[t];
}

__global__ __launch_bounds__(256) void scan_phase3(
    const int* __restrict__ block_sums, int* __restrict__ row_start,
    int* __restrict__ cursor) {
    int i = blockIdx.x * SCAN_CHUNK + threadIdx.x;
    if (i < N_NODES) {
        int v = row_start[i] + block_sums[blockIdx.x];
        row_start[i] = v;
        cursor[i] = v;
    }
}

__global__ void fill_edges(const int* __restrict__ src, const int* __restrict__ dst,
                           int* __restrict__ cursor, int* __restrict__ edge_src) {
    int e = blockIdx.x * 256 + threadIdx.x;
    if (e < N_EDGES) {
        int p = atomicAdd(&cursor[dst[e]], 1);
        edge_src[p] = src[e];
    }
}

// ---------------- fused layer: mean-agg into LDS + dual MFMA GEMM -----------
// block = 32 nodes, 512 threads (8 waves), grid 1250.
// phase A: wave w aggregates nodes w*4..w*4+3; padded CSR -> branch-free
//          16-deep batches, aligned int4 index loads, 16 row loads in flight.
// phase B: wave w computes rows (w>>2)*16..+15, cols (w&3)*32..+31;
//          self operand global, neigh operand from LDS mean tile.
// phase C: stage acc to LDS, vectorized bias(+relu) epilogue.

#define PADW 68   // dwords per mean row in LDS (64 data + 4 pad); 272 B, 16B-mult

__global__ __launch_bounds__(512) void fused_layer(
    const unsigned short* __restrict__ A,     // bf16 plane [N_NODES+1][128]
    const int* __restrict__ row_start,        // padded offsets
    const int* __restrict__ deg,              // true degrees
    const int* __restrict__ edge_src,         // padded, sentinel = N_NODES
    const unsigned* __restrict__ Wp,          // 16384 uints, fragment order
    const float* __restrict__ bias,
    unsigned short* __restrict__ outb,        // bf16 out (layer 1) or nullptr
    float* __restrict__ outf,                 // f32 out (layer 2) or nullptr
    int do_relu) {
    __shared__ float sf[32 * 132];            // 16896 B; aliased as mean tile
    unsigned* meanL = (unsigned*)sf;          // [32][PADW]

    int tid = threadIdx.x;
    int w = tid >> 6, l = tid & 63;
    int blk = blockIdx.x;
    const unsigned* h4 = (const unsigned*)A;  // 64 dwords per row

    // ---- phase A ----
    int n0 = blk * 32 + w * 4;
    int es[5];
    #pragma unroll
    for (int g = 0; g < 5; ++g) es[g] = row_start[n0 + g];
    int dg[4];
    #pragma unroll
    for (int g = 0; g < 4; ++g) dg[g] = deg[n0 + g];

    #pragma unroll
    for (int g = 0; g < 4; ++g) {
        float a0 = 0.f, a1 = 0.f;
        for (int e = es[g]; e < es[g + 1]; e += 16) {
            int4 q0 = *(const int4*)&edge_src[e];
            int4 q1 = *(const int4*)&edge_src[e + 4];
            int4 q2 = *(const int4*)&edge_src[e + 8];
            int4 q3 = *(const int4*)&edge_src[e + 12];
            unsigned u0  = h4[(size_t)q0.x * 64 + l];
            unsigned u1  = h4[(size_t)q0.y * 64 + l];
            unsigned u2  = h4[(size_t)q0.z * 64 + l];
            unsigned u3  = h4[(size_t)q0.w * 64 + l];
            unsigned u4  = h4[(size_t)q1.x * 64 + l];
            unsigned u5  = h4[(size_t)q1.y * 64 + l];
            unsigned u6  = h4[(size_t)q1.z * 64 + l];
            unsigned u7  = h4[(size_t)q1.w * 64 + l];
            unsigned u8  = h4[(size_t)q2.x * 64 + l];
            unsigned u9  = h4[(size_t)q2.y * 64 + l];
            unsigned u10 = h4[(size_t)q2.z * 64 + l];
            unsigned u11 = h4[(size_t)q2.w * 64 + l];
            unsigned u12 = h4[(size_t)q3.x * 64 + l];
            unsigned u13 = h4[(size_t)q3.y * 64 + l];
            unsigned u14 = h4[(size_t)q3.z * 64 + l];
            unsigned u15 = h4[(size_t)q3.w * 64 + l];
            a0 += BF_LO(u0) + BF_LO(u1) + BF_LO(u2) + BF_LO(u3)
                + BF_LO(u4) + BF_LO(u5) + BF_LO(u6) + BF_LO(u7)
                + BF_LO(u8) + BF_LO(u9) + BF_LO(u10) + BF_LO(u11)
                + BF_LO(u12) + BF_LO(u13) + BF_LO(u14) + BF_LO(u15);
            a1 += BF_HI(u0) + BF_HI(u1) + BF_HI(u2) + BF_HI(u3)
                + BF_HI(u4) + BF_HI(u5) + BF_HI(u6) + BF_HI(u7)
                + BF_HI(u8) + BF_HI(u9) + BF_HI(u10) + BF_HI(u11)
                + BF_HI(u12) + BF_HI(u13) + BF_HI(u14) + BF_HI(u15);
        }
        float inv = dg[g] > 0 ? 1.0f / (float)dg[g] : 0.f;
        meanL[(w * 4 + g) * PADW + l] =
            f2bf(a0 * inv) | ((unsigned)f2bf(a1 * inv) << 16);
    }

    // ---- phase B: dual GEMM ----
    int rlo = l & 15, khi = l >> 4;
    int row0g = blk * 32 + (w >> 2) * 16;
    const unsigned short* ar = A + (size_t)(row0g + rlo) * D + khi * 8;

    f32x4 acc[2] = {};
    // self half first: no LDS dependence -> runs before the barrier
    #pragma unroll
    for (int q = 0; q < 4; ++q) {
        short8 a = *(const short8*)(ar + q * 32);
        #pragma unroll
        for (int c = 0; c < 2; ++c) {
            int cg = (w & 3) * 2 + c;
            short8 b = *(const short8*)(Wp + ((q * 8 + cg) * 64 + l) * 4);
            acc[c] = __builtin_amdgcn_mfma_f32_16x16x32_bf16(a, b, acc[c], 0, 0, 0);
        }
    }
    __syncthreads();
    // neigh half from LDS mean tile
    int lr0 = (w >> 2) * 16 + rlo;
    #pragma unroll
    for (int q = 4; q < 8; ++q) {
        short8 a = *(const short8*)(meanL + lr0 * PADW + khi * 4 + (q & 3) * 16);
        #pragma unroll
        for (int c = 0; c < 2; ++c) {
            int cg = (w & 3) * 2 + c;
            short8 b = *(const short8*)(Wp + ((q * 8 + cg) * 64 + l) * 4);
            acc[c] = __builtin_amdgcn_mfma_f32_16x16x32_bf16(a, b, acc[c], 0, 0, 0);
        }
    }
    __syncthreads();   // all reads of meanL done before sf overwrite

    // ---- phase C: epilogue via LDS stage ----
    #pragma unroll
    for (int c = 0; c < 2; ++c) {
        int cg = (w & 3) * 2 + c;
        #pragma unroll
        for (int j = 0; j < 4; ++j)
            sf[((w >> 2) * 16 + khi * 4 + j) * 132 + cg * 16 + rlo] = acc[c][j];
    }
    __syncthreads();

    int row = tid >> 4, c0 = (tid & 15) * 8;
    const float* srow = &sf[row * 132 + c0];
    float4 u0 = *(const float4*)(srow + 0);
    float4 u1 = *(const float4*)(srow + 4);
    float4 b0 = *(const float4*)(bias + c0 + 0);
    float4 b1 = *(const float4*)(bias + c0 + 4);
    size_t grow = (size_t)blk * 32 + row;
    if (do_relu) {
        float f0 = fmaxf(u0.x + b0.x, 0.f), f1 = fmaxf(u0.y + b0.y, 0.f);
        float f2 = fmaxf(u0.z + b0.z, 0.f), f3 = fmaxf(u0.w + b0.w, 0.f);
        float f4 = fmaxf(u1.x + b1.x, 0.f), f5 = fmaxf(u1.y + b1.y, 0.f);
        float f6 = fmaxf(u1.z + b1.z, 0.f), f7 = fmaxf(u1.w + b1.w, 0.f);
        uint4 o;
        o.x = f2bf(f0) | ((unsigned)f2bf(f1) << 16);
        o.y = f2bf(f2) | ((unsigned)f2bf(f3) << 16);
        o.z = f2bf(f4) | ((unsigned)f2bf(f5) << 16);
        o.w = f2bf(f6) | ((unsigned)f2bf(f7) << 16);
        *(uint4*)(outb + grow * D + c0) = o;
    } else {
        float4 o0 = {u0.x + b0.x, u0.y + b0.y, u0.z + b0.z, u0.w + b0.w};
        float4 o1 = {u1.x + b1.x, u1.y + b1.y, u1.z + b1.z, u1.w + b1.w};
        *(float4*)(outf + grow * D + c0 + 0) = o0;
        *(float4*)(outf + grow * D + c0 + 4) = o1;
    }
}

// ---------------- launch ----------------

extern "C" void kernel_launch(void* const* d_in, const int* in_sizes, int n_in,
                              void* d_out, int out_size, void* d_ws, size_t ws_size,
                              hipStream_t stream) {
    const float* x       = (const float*)d_in[0];
    const int*   src     = (const int*)d_in[1];
    const int*   dst     = (const int*)d_in[2];
    const float* W_self1 = (const float*)d_in[3];
    const float* W_neigh1= (const float*)d_in[4];
    const float* b1      = (const float*)d_in[5];
    const float* W_self2 = (const float*)d_in[6];
    const float* W_neigh2= (const float*)d_in[7];
    const float* b2      = (const float*)d_in[8];
    float* out = (float*)d_out;

    char* ws = (char*)d_ws;
    size_t off_deg  = 0;                        // 40000 int
    size_t off_rs   = off_deg  + 160000;        // 40001 int
    size_t off_cur  = off_rs   + 160016;        // 40000 int
    size_t off_es   = off_cur  + 160000;        // ES_CAP int
    size_t off_xb   = off_es   + 5120000;       // (40000+1)*128 bf16
    size_t off_h1b  = off_xb   + 10240256;      // (40000+1)*128 bf16
    size_t off_wp   = off_h1b  + 10240256;      // 2*16384 uint
    size_t off_bs   = off_wp   + 131072;        // 157 int
    size_t total    = off_bs   + 640;
    if (ws_size < total) return;

    int* deg       = (int*)(ws + off_deg);
    int* row_start = (int*)(ws + off_rs);
    int* cursor    = (int*)(ws + off_cur);
    int* edge_src  = (int*)(ws + off_es);
    unsigned short* xb   = (unsigned short*)(ws + off_xb);
    unsigned short* h1b  = (unsigned short*)(ws + off_h1b);
    unsigned* Wp         = (unsigned*)(ws + off_wp);
    int* block_sums      = (int*)(ws + off_bs);

    hipMemsetAsync(deg, 0, 160000, stream);
    prep_count<<<2500, 256, 0, stream>>>(x, xb, h1b, W_self1, W_neigh1, W_self2,
                                         W_neigh2, Wp, dst, deg, edge_src);
    scan_phase1<<<SCAN_NBLK, 256, 0, stream>>>(deg, row_start, block_sums);
    scan_phase2<<<1, 256, 0, stream>>>(block_sums, row_start);
    scan_phase3<<<SCAN_NBLK, 256, 0, stream>>>(block_sums, row_start, cursor);
    fill_edges<<<(N_EDGES + 255) / 256, 256, 0, stream>>>(src, dst, cursor, edge_src);

    fused_layer<<<N_NODES / 32, 512, 0, stream>>>(xb, row_start, deg, edge_src,
                                                  Wp, b1, h1b, nullptr, 1);
    fused_layer<<<N_NODES / 32, 512, 0, stream>>>(h1b, row_start, deg, edge_src,
                                                  Wp + 16384, b2, nullptr, out, 0);
}

// Round 7
// 139.469 us; speedup vs baseline: 2.3987x; 1.0397x over previous
//
#include <hip/hip_runtime.h>

#define N_NODES 40000
#define N_EDGES 640000
#define D 128
#define ES_CAP 1280000   // padded edge capacity: 640000 + 40000*15 = 1.24M max

typedef __attribute__((ext_vector_type(8))) short short8;   // 8 bf16 = 4 VGPR
typedef __attribute__((ext_vector_type(4))) float f32x4;

__device__ __forceinline__ unsigned short f2bf(float f) {
    unsigned u = __float_as_uint(f);
    unsigned r = u + 0x7FFF + ((u >> 16) & 1);   // round-to-nearest-even
    return (unsigned short)(r >> 16);
}

#define BF_LO(u) __uint_as_float((u) << 16)
#define BF_HI(u) __uint_as_float((u) & 0xFFFF0000u)

// ---------------- fused prep: x->bf16, weight pack, degree count, ----------
// ---------------- edge_src sentinel fill, zero pad-rows ---------------------
// grid 2500 x 256 = 640000 threads. deg must be zeroed beforehand (memset).

__global__ __launch_bounds__(256) void prep_count(
    const float* __restrict__ x, unsigned short* __restrict__ xb,
    unsigned short* __restrict__ h1b,
    const float* __restrict__ Ws1, const float* __restrict__ Wn1,
    const float* __restrict__ Ws2, const float* __restrict__ Wn2,
    unsigned* __restrict__ Wp, const int* __restrict__ dst,
    int* __restrict__ deg, int* __restrict__ edge_src) {
    int t = blockIdx.x * 256 + threadIdx.x;

    // sentinel-fill padded edge array (2 slots/thread covers ES_CAP)
    edge_src[t] = N_NODES;
    edge_src[t + 640000] = N_NODES;

    // zero the sentinel row of both feature planes (row N_NODES)
    if (t < 64) {
        ((unsigned*)xb)[N_NODES * 64 + t] = 0;
        ((unsigned*)h1b)[N_NODES * 64 + t] = 0;
    }

    // fp32 -> bf16 feature plane (8 elems/thread)
    {
        float4 a = ((const float4*)x)[t * 2];
        float4 b = ((const float4*)x)[t * 2 + 1];
        uint4 o;
        o.x = f2bf(a.x) | ((unsigned)f2bf(a.y) << 16);
        o.y = f2bf(a.z) | ((unsigned)f2bf(a.w) << 16);
        o.z = f2bf(b.x) | ((unsigned)f2bf(b.y) << 16);
        o.w = f2bf(b.z) | ((unsigned)f2bf(b.w) << 16);
        ((uint4*)xb)[t] = o;
    }

    // degree count (1 edge/thread)
    atomicAdd(&deg[dst[t]], 1);

    // weight pre-pack into MFMA B-fragment order:
    // element (((q*8+c)*64+l)*8 + j) = W[(q&3)*32 + (l>>4)*8 + j][c*16 + (l&15)]
    if (t < 32768) {
        int L   = t >> 14;
        int rem = t & 16383;
        int j2 = rem & 3;
        int l  = (rem >> 2) & 63;
        int c  = (rem >> 8) & 7;
        int q  = rem >> 11;
        const float* W = (L == 0) ? (q < 4 ? Ws1 : Wn1) : (q < 4 ? Ws2 : Wn2);
        int k0  = (q & 3) * 32 + (l >> 4) * 8 + 2 * j2;
        int col = c * 16 + (l & 15);
        float v0 = W[(size_t)k0 * D + col];
        float v1 = W[(size_t)(k0 + 1) * D + col];
        Wp[t] = f2bf(v0) | ((unsigned)f2bf(v1) << 16);
    }
}

// ---------------- CSR scan over PADDED degrees (multiples of 16) ------------

#define SCAN_CHUNK 256
#define SCAN_NBLK ((N_NODES + SCAN_CHUNK - 1) / SCAN_CHUNK)  // 157

__global__ __launch_bounds__(256) void scan_phase1(
    const int* __restrict__ deg, int* __restrict__ row_start,
    int* __restrict__ block_sums) {
    __shared__ int s[SCAN_CHUNK];
    int t = threadIdx.x;
    int i = blockIdx.x * SCAN_CHUNK + t;
    int v = (i < N_NODES) ? ((deg[i] + 15) & ~15) : 0;   // padded degree
    s[t] = v;
    __syncthreads();
    for (int off = 1; off < SCAN_CHUNK; off <<= 1) {
        int u = 0;
        if (t >= off) u = s[t - off];
        __syncthreads();
        if (t >= off) s[t] += u;
        __syncthreads();
    }
    if (i < N_NODES) row_start[i] = s[t] - v;
    if (t == SCAN_CHUNK - 1) block_sums[blockIdx.x] = s[t];
}

__global__ __launch_bounds__(256) void scan_phase2(
    int* __restrict__ block_sums, int* __restrict__ row_start) {
    __shared__ int s[256];
    int t = threadIdx.x;
    int v = (t < SCAN_NBLK) ? block_sums[t] : 0;
    s[t] = v;
    __syncthreads();
    for (int off = 1; off < 256; off <<= 1) {
        int u = 0;
        if (t >= off) u = s[t - off];
        __syncthreads();
        if (t >= off) s[t] += u;
        __syncthreads();
    }
    if (t < SCAN_NBLK) block_sums[t] = s[t] - v;
    if (t == SCAN_NBLK - 1) row_start[N_NODES] = s[t];
}

__global__ __launch_bounds__(256) void scan_phase3(
    const int* __restrict__ block_sums, int* __restrict__ row_start,
    int* __restrict__ cursor) {
    int i = blockIdx.x * SCAN_CHUNK + threadIdx.x;
    if (i < N_NODES) {
        int v = row_start[i] + block_sums[blockIdx.x];
        row_start[i] = v;
        cursor[i] = v;
    }
}

__global__ void fill_edges(const int* __restrict__ src, const int* __restrict__ dst,
                           int* __restrict__ cursor, int* __restrict__ edge_src) {
    int e = blockIdx.x * 256 + threadIdx.x;
    if (e < N_EDGES) {
        int p = atomicAdd(&cursor[dst[e]], 1);
        edge_src[p] = src[e];
    }
}

// ---------------- fused layer: mean-agg into LDS + dual MFMA GEMM -----------
// block = 32 nodes, 512 threads (8 waves), grid 1250.
// phase A: wave w aggregates nodes w*4..w*4+3. 16-edge batches: 1 coalesced
//          int4 index load + 4 uint4 gathers (each instr = 4 complete rows,
//          1 KB per vmcnt slot). Lane-group g=lane>>4 covers edges e+4g..+3,
//          lane covers feature-dwords (lane&15)*4..+3. __shfl_xor(16/32)
//          folds the 4 groups; lanes 0-15 write the mean row to LDS.
// phase B: wave w computes rows (w>>2)*16..+15, cols (w&3)*32..+31;
//          self operand global, neigh operand from LDS mean tile.
// phase C: stage acc to LDS, vectorized bias(+relu) epilogue.

#define PADW 68   // dwords per mean row in LDS (64 data + 4 pad)

__global__ __launch_bounds__(512) void fused_layer(
    const unsigned short* __restrict__ A,     // bf16 plane [N_NODES+1][128]
    const int* __restrict__ row_start,        // padded offsets
    const int* __restrict__ deg,              // true degrees
    const int* __restrict__ edge_src,         // padded, sentinel = N_NODES
    const unsigned* __restrict__ Wp,          // 16384 uints, fragment order
    const float* __restrict__ bias,
    unsigned short* __restrict__ outb,        // bf16 out (layer 1) or nullptr
    float* __restrict__ outf,                 // f32 out (layer 2) or nullptr
    int do_relu) {
    __shared__ float sf[32 * 132];            // 16896 B; aliased as mean tile
    unsigned* meanL = (unsigned*)sf;          // [32][PADW]

    int tid = threadIdx.x;
    int w = tid >> 6, l = tid & 63;
    int blk = blockIdx.x;
    const uint4* h16 = (const uint4*)A;       // 16 uint4 per 256 B row
    int grp = l >> 4, sub = l & 15;

    // ---- phase A ----
    int n0 = blk * 32 + w * 4;
    int es[5];
    #pragma unroll
    for (int g = 0; g < 5; ++g) es[g] = row_start[n0 + g];
    int dg[4];
    #pragma unroll
    for (int g = 0; g < 4; ++g) dg[g] = deg[n0 + g];

    for (int g = 0; g < 4; ++g) {
        float a0 = 0.f, a1 = 0.f, a2 = 0.f, a3 = 0.f;
        float a4 = 0.f, a5 = 0.f, a6 = 0.f, a7 = 0.f;
        for (int e = es[g]; e < es[g + 1]; e += 16) {
            int4 q = *(const int4*)&edge_src[e + (grp << 2)];
            uint4 u0 = h16[(size_t)q.x * 16 + sub];
            uint4 u1 = h16[(size_t)q.y * 16 + sub];
            uint4 u2 = h16[(size_t)q.z * 16 + sub];
            uint4 u3 = h16[(size_t)q.w * 16 + sub];
            a0 += BF_LO(u0.x) + BF_LO(u1.x) + BF_LO(u2.x) + BF_LO(u3.x);
            a1 += BF_HI(u0.x) + BF_HI(u1.x) + BF_HI(u2.x) + BF_HI(u3.x);
            a2 += BF_LO(u0.y) + BF_LO(u1.y) + BF_LO(u2.y) + BF_LO(u3.y);
            a3 += BF_HI(u0.y) + BF_HI(u1.y) + BF_HI(u2.y) + BF_HI(u3.y);
            a4 += BF_LO(u0.z) + BF_LO(u1.z) + BF_LO(u2.z) + BF_LO(u3.z);
            a5 += BF_HI(u0.z) + BF_HI(u1.z) + BF_HI(u2.z) + BF_HI(u3.z);
            a6 += BF_LO(u0.w) + BF_LO(u1.w) + BF_LO(u2.w) + BF_LO(u3.w);
            a7 += BF_HI(u0.w) + BF_HI(u1.w) + BF_HI(u2.w) + BF_HI(u3.w);
        }
        // fold the 4 lane-groups (edges are all the same node's)
        a0 += __shfl_xor(a0, 16, 64); a0 += __shfl_xor(a0, 32, 64);
        a1 += __shfl_xor(a1, 16, 64); a1 += __shfl_xor(a1, 32, 64);
        a2 += __shfl_xor(a2, 16, 64); a2 += __shfl_xor(a2, 32, 64);
        a3 += __shfl_xor(a3, 16, 64); a3 += __shfl_xor(a3, 32, 64);
        a4 += __shfl_xor(a4, 16, 64); a4 += __shfl_xor(a4, 32, 64);
        a5 += __shfl_xor(a5, 16, 64); a5 += __shfl_xor(a5, 32, 64);
        a6 += __shfl_xor(a6, 16, 64); a6 += __shfl_xor(a6, 32, 64);
        a7 += __shfl_xor(a7, 16, 64); a7 += __shfl_xor(a7, 32, 64);
        if (grp == 0) {
            float inv = dg[g] > 0 ? 1.0f / (float)dg[g] : 0.f;
            uint4 o;
            o.x = f2bf(a0 * inv) | ((unsigned)f2bf(a1 * inv) << 16);
            o.y = f2bf(a2 * inv) | ((unsigned)f2bf(a3 * inv) << 16);
            o.z = f2bf(a4 * inv) | ((unsigned)f2bf(a5 * inv) << 16);
            o.w = f2bf(a6 * inv) | ((unsigned)f2bf(a7 * inv) << 16);
            *(uint4*)&meanL[(w * 4 + g) * PADW + sub * 4] = o;
        }
    }

    // ---- phase B: dual GEMM ----
    int rlo = l & 15, khi = l >> 4;
    int row0g = blk * 32 + (w >> 2) * 16;
    const unsigned short* ar = A + (size_t)(row0g + rlo) * D + khi * 8;

    f32x4 acc[2] = {};
    // self half first: no LDS dependence -> runs before the barrier
    #pragma unroll
    for (int q = 0; q < 4; ++q) {
        short8 a = *(const short8*)(ar + q * 32);
        #pragma unroll
        for (int c = 0; c < 2; ++c) {
            int cg = (w & 3) * 2 + c;
            short8 b = *(const short8*)(Wp + ((q * 8 + cg) * 64 + l) * 4);
            acc[c] = __builtin_amdgcn_mfma_f32_16x16x32_bf16(a, b, acc[c], 0, 0, 0);
        }
    }
    __syncthreads();
    // neigh half from LDS mean tile
    int lr0 = (w >> 2) * 16 + rlo;
    #pragma unroll
    for (int q = 4; q < 8; ++q) {
        short8 a = *(const short8*)(meanL + lr0 * PADW + khi * 4 + (q & 3) * 16);
        #pragma unroll
        for (int c = 0; c < 2; ++c) {
            int cg = (w & 3) * 2 + c;
            short8 b = *(const short8*)(Wp + ((q * 8 + cg) * 64 + l) * 4);
            acc[c] = __builtin_amdgcn_mfma_f32_16x16x32_bf16(a, b, acc[c], 0, 0, 0);
        }
    }
    __syncthreads();   // all reads of meanL done before sf overwrite

    // ---- phase C: epilogue via LDS stage ----
    #pragma unroll
    for (int c = 0; c < 2; ++c) {
        int cg = (w & 3) * 2 + c;
        #pragma unroll
        for (int j = 0; j < 4; ++j)
            sf[((w >> 2) * 16 + khi * 4 + j) * 132 + cg * 16 + rlo] = acc[c][j];
    }
    __syncthreads();

    int row = tid >> 4, c0 = (tid & 15) * 8;
    const float* srow = &sf[row * 132 + c0];
    float4 u0 = *(const float4*)(srow + 0);
    float4 u1 = *(const float4*)(srow + 4);
    float4 b0 = *(const float4*)(bias + c0 + 0);
    float4 b1 = *(const float4*)(bias + c0 + 4);
    size_t grow = (size_t)blk * 32 + row;
    if (do_relu) {
        float f0 = fmaxf(u0.x + b0.x, 0.f), f1 = fmaxf(u0.y + b0.y, 0.f);
        float f2 = fmaxf(u0.z + b0.z, 0.f), f3 = fmaxf(u0.w + b0.w, 0.f);
        float f4 = fmaxf(u1.x + b1.x, 0.f), f5 = fmaxf(u1.y + b1.y, 0.f);
        float f6 = fmaxf(u1.z + b1.z, 0.f), f7 = fmaxf(u1.w + b1.w, 0.f);
        uint4 o;
        o.x = f2bf(f0) | ((unsigned)f2bf(f1) << 16);
        o.y = f2bf(f2) | ((unsigned)f2bf(f3) << 16);
        o.z = f2bf(f4) | ((unsigned)f2bf(f5) << 16);
        o.w = f2bf(f6) | ((unsigned)f2bf(f7) << 16);
        *(uint4*)(outb + grow * D + c0) = o;
    } else {
        float4 o0 = {u0.x + b0.x, u0.y + b0.y, u0.z + b0.z, u0.w + b0.w};
        float4 o1 = {u1.x + b1.x, u1.y + b1.y, u1.z + b1.z, u1.w + b1.w};
        *(float4*)(outf + grow * D + c0 + 0) = o0;
        *(float4*)(outf + grow * D + c0 + 4) = o1;
    }
}

// ---------------- launch ----------------

extern "C" void kernel_launch(void* const* d_in, const int* in_sizes, int n_in,
                              void* d_out, int out_size, void* d_ws, size_t ws_size,
                              hipStream_t stream) {
    const float* x       = (const float*)d_in[0];
    const int*   src     = (const int*)d_in[1];
    const int*   dst     = (const int*)d_in[2];
    const float* W_self1 = (const float*)d_in[3];
    const float* W_neigh1= (const float*)d_in[4];
    const float* b1      = (const float*)d_in[5];
    const float* W_self2 = (const float*)d_in[6];
    const float* W_neigh2= (const float*)d_in[7];
    const float* b2      = (const float*)d_in[8];
    float* out = (float*)d_out;

    char* ws = (char*)d_ws;
    size_t off_deg  = 0;                        // 40000 int
    size_t off_rs   = 160256;                   // 40001 int (256-aligned)
    size_t off_cur  = 320512;                   // 40000 int
    size_t off_es   = 480512;                   // ES_CAP int
    size_t off_xb   = 5600768;                  // (40000+1)*128 bf16, 256-aligned
    size_t off_h1b  = 15841024;                 // (40000+1)*128 bf16
    size_t off_wp   = 26081280;                 // 2*16384 uint
    size_t off_bs   = 26212352;                 // 157 int
    size_t total    = 26213120;
    if (ws_size < total) return;

    int* deg       = (int*)(ws + off_deg);
    int* row_start = (int*)(ws + off_rs);
    int* cursor    = (int*)(ws + off_cur);
    int* edge_src  = (int*)(ws + off_es);
    unsigned short* xb   = (unsigned short*)(ws + off_xb);
    unsigned short* h1b  = (unsigned short*)(ws + off_h1b);
    unsigned* Wp         = (unsigned*)(ws + off_wp);
    int* block_sums      = (int*)(ws + off_bs);

    hipMemsetAsync(deg, 0, 160000, stream);
    prep_count<<<2500, 256, 0, stream>>>(x, xb, h1b, W_self1, W_neigh1, W_self2,
                                         W_neigh2, Wp, dst, deg, edge_src);
    scan_phase1<<<SCAN_NBLK, 256, 0, stream>>>(deg, row_start, block_sums);
    scan_phase2<<<1, 256, 0, stream>>>(block_sums, row_start);
    scan_phase3<<<SCAN_NBLK, 256, 0, stream>>>(block_sums, row_start, cursor);
    fill_edges<<<(N_EDGES + 255) / 256, 256, 0, stream>>>(src, dst, cursor, edge_src);

    fused_layer<<<N_NODES / 32, 512, 0, stream>>>(xb, row_start, deg, edge_src,
                                                  Wp, b1, h1b, nullptr, 1);
    fused_layer<<<N_NODES / 32, 512, 0, stream>>>(h1b, row_start, deg, edge_src,
                                                  Wp + 16384, b2, nullptr, out, 0);
}